// Round 1
// baseline (579.717 us; speedup 1.0000x reference)
//
#include <hip/hip_runtime.h>
#include <hip/hip_bf16.h>
#include <cstdint>

// Problem constants
#define BATCH 2
#define SEQLEN 512
#define BL (BATCH*SEQLEN)       // 1024 rows
#define DMODEL 1024
#define DINNER 2048
#define NHEADS 32
#define HEADDIM 64
#define DSTATE 128
#define CONVDIM 2304            // DINNER + 2*DSTATE
#define DINPROJ 4384            // 2*DINNER + 2*DSTATE + NHEADS
#define NCLS 48

typedef short bf16x8 __attribute__((ext_vector_type(8)));
typedef float f32x4  __attribute__((ext_vector_type(4)));

static __device__ __forceinline__ unsigned short f2bf(float f) {
    unsigned u = __float_as_uint(f);
    unsigned r = (u + 0x7FFFu + ((u >> 16) & 1u)) >> 16;
    return (unsigned short)r;
}

// ---------------- K0a: inputs fp32 -> bf16 (row-major 1024x1024) -------------
__global__ __launch_bounds__(256) void k_cvt_a(const float* __restrict__ in,
                                               unsigned short* __restrict__ out) {
    int i = (blockIdx.x * 256 + threadIdx.x) * 4;   // total BL*DMODEL = 1,048,576
    float4 v = *(const float4*)(in + i);
    ushort4 o;
    o.x = f2bf(v.x); o.y = f2bf(v.y); o.z = f2bf(v.z); o.w = f2bf(v.w);
    *(ushort4*)(out + i) = o;
}

// ---------------- K0b: W_in (1024x4384) -> Wt bf16 (4384x1024) ---------------
__global__ __launch_bounds__(256) void k_transpose_w(const float* __restrict__ W,
                                                     unsigned short* __restrict__ Wt) {
    __shared__ float tile[32][33];
    int n0 = blockIdx.x * 32;   // over 4384
    int k0 = blockIdx.y * 32;   // over 1024
    int tx = threadIdx.x & 31;
    int ty = threadIdx.x >> 5;  // 0..7
#pragma unroll
    for (int i = 0; i < 4; ++i) {
        int k = k0 + ty + i * 8;
        tile[ty + i * 8][tx] = W[(size_t)k * DINPROJ + n0 + tx];
    }
    __syncthreads();
#pragma unroll
    for (int i = 0; i < 4; ++i) {
        int n = n0 + ty + i * 8;
        Wt[(size_t)n * DMODEL + k0 + tx] = f2bf(tile[tx][ty + i * 8]);
    }
}

// ---------------- K1: zxbcdt = A(1024x1024) @ W(1024x4384), bf16 MFMA --------
// A row-major bf16, Bt = W^T (4384x1024) row-major bf16, C fp32 (1024x4384)
// Tile: BM=128, BN=64, BK=32. 4 waves, wave w -> rows [w*32, w*32+32), all 64 N.
__global__ __launch_bounds__(256) void k_gemm_in(const unsigned short* __restrict__ A,
                                                 const unsigned short* __restrict__ Bt,
                                                 float* __restrict__ C) {
    __shared__ unsigned short As[128][40];  // pad 32->40 (2-way b128 reads = free)
    __shared__ unsigned short Bs[64][40];
    const int tid  = threadIdx.x;
    const int m0   = blockIdx.y * 128;
    const int n0   = blockIdx.x * 64;
    const int lr   = tid >> 2;          // 0..63
    const int lc   = (tid & 3) * 8;     // k-offset in ushort
    const int wv   = tid >> 6;          // wave 0..3
    const int lane = tid & 63;
    const int fr   = lane & 15;
    const int fk   = (lane >> 4) * 8;
    f32x4 acc[2][4] = {};
    for (int k0 = 0; k0 < DMODEL; k0 += 32) {
        __syncthreads();
        *(uint4*)(&As[lr][lc])      = *(const uint4*)(A + (size_t)(m0 + lr) * DMODEL + k0 + lc);
        *(uint4*)(&As[lr + 64][lc]) = *(const uint4*)(A + (size_t)(m0 + lr + 64) * DMODEL + k0 + lc);
        int n = n0 + lr;
        uint4 bv = make_uint4(0u, 0u, 0u, 0u);
        if (n < DINPROJ) bv = *(const uint4*)(Bt + (size_t)n * DMODEL + k0 + lc);
        *(uint4*)(&Bs[lr][lc]) = bv;
        __syncthreads();
        bf16x8 af0 = *(const bf16x8*)(&As[wv * 32 + fr][fk]);
        bf16x8 af1 = *(const bf16x8*)(&As[wv * 32 + 16 + fr][fk]);
        bf16x8 bfr[4];
#pragma unroll
        for (int nt = 0; nt < 4; ++nt) bfr[nt] = *(const bf16x8*)(&Bs[nt * 16 + fr][fk]);
#pragma unroll
        for (int nt = 0; nt < 4; ++nt) {
            acc[0][nt] = __builtin_amdgcn_mfma_f32_16x16x32_bf16(af0, bfr[nt], acc[0][nt], 0, 0, 0);
            acc[1][nt] = __builtin_amdgcn_mfma_f32_16x16x32_bf16(af1, bfr[nt], acc[1][nt], 0, 0, 0);
        }
    }
    const int r4 = (lane >> 4) * 4;
#pragma unroll
    for (int mt = 0; mt < 2; ++mt) {
#pragma unroll
        for (int nt = 0; nt < 4; ++nt) {
            int col = n0 + nt * 16 + fr;
            if (col < DINPROJ) {
#pragma unroll
                for (int r = 0; r < 4; ++r) {
                    int row = m0 + wv * 32 + mt * 16 + r4 + r;
                    C[(size_t)row * DINPROJ + col] = acc[mt][nt][r];
                }
            }
        }
    }
}

// ---------------- K2: causal depthwise conv + silu, and dt/dA ----------------
// xbc[row][c] = silu(conv_b[c] + sum_j zx[row(l-3+j)][2048+c]*conv_w[c][j]), c<2304
// dt[row][h] = softplus(zx[row][4352+h] + dt_bias[h]); dA = exp(dt * -exp(A_log))
__global__ __launch_bounds__(256) void k_conv_dt(const float* __restrict__ zx,
                                                 const float* __restrict__ conv_w,
                                                 const float* __restrict__ conv_b,
                                                 const float* __restrict__ dt_bias,
                                                 const float* __restrict__ A_log,
                                                 float* __restrict__ xbc,
                                                 float* __restrict__ dtb,
                                                 float* __restrict__ dab) {
    int row = blockIdx.y;                 // b*512 + l
    int c   = blockIdx.x * 256 + threadIdx.x;
    int b = row >> 9, l = row & 511;
    if (c < CONVDIM) {
        float acc = conv_b[c];
#pragma unroll
        for (int j = 0; j < 4; ++j) {
            int ls = l - 3 + j;
            float v = (ls >= 0) ? zx[((size_t)(b * SEQLEN + ls)) * DINPROJ + DINNER + c] : 0.f;
            acc += v * conv_w[c * 4 + j];
        }
        float s = acc / (1.f + expf(-acc));
        xbc[(size_t)row * CONVDIM + c] = s;
    } else if (c < CONVDIM + NHEADS) {
        int h = c - CONVDIM;
        float raw = zx[(size_t)row * DINPROJ + (DINNER + CONVDIM) + h] + dt_bias[h];
        float dt = (raw > 20.f) ? raw : log1pf(expf(raw));
        float Ah = -expf(A_log[h]);
        dtb[row * NHEADS + h] = dt;
        dab[row * NHEADS + h] = expf(dt * Ah);
    }
}

// ---------------- K3: selective scan ----------------------------------------
// One WG (512 thr = 8 waves) per (b,h). lane = p (0..63), wave w = n-chunk of 16.
// State s[16] in regs. B/C/dt/dA are wave-uniform -> scalar loads.
__global__ __launch_bounds__(512) void k_scan(const float* __restrict__ xbc,
                                              const float* __restrict__ dtb,
                                              const float* __restrict__ dab,
                                              const float* __restrict__ Dvec,
                                              float* __restrict__ y) {
    const int b = blockIdx.x >> 5;
    const int h = blockIdx.x & 31;
    const int tid = threadIdx.x;
    const int w = __builtin_amdgcn_readfirstlane(tid >> 6);  // 0..7, wave-uniform
    const int p = tid & 63;
    __shared__ float red[8][64];
    float s[16];
#pragma unroll
    for (int j = 0; j < 16; ++j) s[j] = 0.f;
    const float Dh = Dvec[h];
    const float* xrow = xbc + (size_t)b * SEQLEN * CONVDIM + h * HEADDIM;
    const float* Brow = xbc + (size_t)b * SEQLEN * CONVDIM + DINNER + w * 16;
    const float* Crow = Brow + DSTATE;
    const float* dtp  = dtb + (size_t)b * SEQLEN * NHEADS + h;
    const float* dap  = dab + (size_t)b * SEQLEN * NHEADS + h;
    float* yrow = y + (size_t)b * SEQLEN * DINNER + h * HEADDIM + p;
    for (int l = 0; l < SEQLEN; ++l) {
        const float dt_v = dtp[(size_t)l * NHEADS];
        const float da_v = dap[(size_t)l * NHEADS];
        const float xv   = xrow[(size_t)l * CONVDIM + p];
        float Bv[16], Cv[16];
#pragma unroll
        for (int j = 0; j < 16; ++j) {
            Bv[j] = Brow[(size_t)l * CONVDIM + j];
            Cv[j] = Crow[(size_t)l * CONVDIM + j];
        }
        const float xdt = xv * dt_v;
        float acc = 0.f;
#pragma unroll
        for (int j = 0; j < 16; ++j) {
            s[j] = s[j] * da_v + xdt * Bv[j];
            acc += s[j] * Cv[j];
        }
        red[w][p] = acc;
        __syncthreads();
        if (tid < 64) {
            float ysum = 0.f;
#pragma unroll
            for (int ww = 0; ww < 8; ++ww) ysum += red[ww][p];
            yrow[(size_t)l * DINNER] = ysum + Dh * xv;
        }
        __syncthreads();
    }
}

// ---------------- K4a: gated RMSNorm (in-place over y) -----------------------
__global__ __launch_bounds__(256) void k_gate_norm(const float* __restrict__ zx,
                                                   const float* __restrict__ nw,
                                                   float* __restrict__ y) {
    int row = blockIdx.x;
    int tid = threadIdx.x;
    const float* zrow = zx + (size_t)row * DINPROJ;   // z = cols [0,2048)
    float* yr = y + (size_t)row * DINNER;
    float g[8];
    float ss = 0.f;
#pragma unroll
    for (int i = 0; i < 2; ++i) {
        int c = tid * 4 + i * 1024;
        float4 yv = *(const float4*)(yr + c);
        float4 zv = *(const float4*)(zrow + c);
        float zs[4] = {zv.x, zv.y, zv.z, zv.w};
        float ys[4] = {yv.x, yv.y, yv.z, yv.w};
#pragma unroll
        for (int k = 0; k < 4; ++k) {
            float sil = zs[k] / (1.f + expf(-zs[k]));
            float gg = ys[k] * sil;
            g[i * 4 + k] = gg;
            ss += gg * gg;
        }
    }
#pragma unroll
    for (int off = 32; off >= 1; off >>= 1) ss += __shfl_xor(ss, off, 64);
    __shared__ float wsum[4];
    if ((tid & 63) == 0) wsum[tid >> 6] = ss;
    __syncthreads();
    float tot = wsum[0] + wsum[1] + wsum[2] + wsum[3];
    float scale = rsqrtf(tot / (float)DINNER + 1e-5f);
#pragma unroll
    for (int i = 0; i < 2; ++i) {
        int c = tid * 4 + i * 1024;
        float4 nv = *(const float4*)(nw + c);
        float4 o;
        o.x = g[i * 4 + 0] * scale * nv.x;
        o.y = g[i * 4 + 1] * scale * nv.y;
        o.z = g[i * 4 + 2] * scale * nv.z;
        o.w = g[i * 4 + 3] * scale * nv.w;
        *(float4*)(yr + c) = o;
    }
}

// ---------------- K4b: classifier: out = G @ W_cls + b -----------------------
// One wave per 2 rows; lane j (<48). G-row values are uniform -> s_loads.
__global__ __launch_bounds__(64) void k_cls(const float* __restrict__ G,
                                            const float* __restrict__ W,
                                            const float* __restrict__ bcls,
                                            float* __restrict__ out) {
    int r0 = blockIdx.x * 2;
    int j  = threadIdx.x;           // 0..63
    int jj = j < NCLS ? j : NCLS - 1;
    const float* g0 = G + (size_t)r0 * DINNER;
    const float* g1 = g0 + DINNER;
    float a0 = 0.f, a1 = 0.f;
    for (int k = 0; k < DINNER; ++k) {
        float wv = W[(size_t)k * NCLS + jj];
        a0 += g0[k] * wv;
        a1 += g1[k] * wv;
    }
    if (j < NCLS) {
        float bb = bcls[j];
        out[(size_t)r0 * NCLS + j]        = a0 + bb;
        out[(size_t)(r0 + 1) * NCLS + j]  = a1 + bb;
    }
}

// ---------------- launch -----------------------------------------------------
extern "C" void kernel_launch(void* const* d_in, const int* in_sizes, int n_in,
                              void* d_out, int out_size, void* d_ws, size_t ws_size,
                              hipStream_t stream) {
    const float* inputs  = (const float*)d_in[0];
    const float* W_in    = (const float*)d_in[1];
    const float* conv_w  = (const float*)d_in[2];
    const float* conv_b  = (const float*)d_in[3];
    const float* dt_bias = (const float*)d_in[4];
    const float* A_log   = (const float*)d_in[5];
    const float* Dvec    = (const float*)d_in[6];
    const float* norm_w  = (const float*)d_in[7];
    // d_in[8] = W_out (unused by reference output)
    const float* W_cls   = (const float*)d_in[9];
    const float* b_cls   = (const float*)d_in[10];
    float* out = (float*)d_out;

    // workspace layout (floats); total ~47.1 MB
    float* ws  = (float*)d_ws;
    float* zx  = ws;                           // BL*4384
    float* xbc = zx  + (size_t)BL * DINPROJ;   // BL*2304
    float* dtb = xbc + (size_t)BL * CONVDIM;   // BL*32
    float* dab = dtb + (size_t)BL * NHEADS;    // BL*32
    float* yb  = dab + (size_t)BL * NHEADS;    // BL*2048 (G written in-place later)
    unsigned short* abf  = (unsigned short*)(yb + (size_t)BL * DINNER);  // BL*1024
    unsigned short* wtbf = abf + (size_t)BL * DMODEL;                    // 4384*1024

    k_cvt_a<<<dim3(BL * DMODEL / (256 * 4)), dim3(256), 0, stream>>>(inputs, abf);
    k_transpose_w<<<dim3(DINPROJ / 32, DMODEL / 32), dim3(256), 0, stream>>>(W_in, wtbf);
    k_gemm_in<<<dim3((DINPROJ + 63) / 64, BL / 128), dim3(256), 0, stream>>>(abf, wtbf, zx);
    k_conv_dt<<<dim3(10, BL), dim3(256), 0, stream>>>(zx, conv_w, conv_b, dt_bias, A_log,
                                                      xbc, dtb, dab);
    k_scan<<<dim3(BATCH * NHEADS), dim3(512), 0, stream>>>(xbc, dtb, dab, Dvec, yb);
    k_gate_norm<<<dim3(BL), dim3(256), 0, stream>>>(zx, norm_w, yb);
    k_cls<<<dim3(BL / 2), dim3(64), 0, stream>>>(yb, W_cls, b_cls, out);
}

// Round 2
// 317.347 us; speedup vs baseline: 1.8268x; 1.8268x over previous
//
#include <hip/hip_runtime.h>
#include <hip/hip_bf16.h>
#include <cstdint>

// Problem constants
#define BATCH 2
#define SEQLEN 512
#define BL (BATCH*SEQLEN)       // 1024 rows
#define DMODEL 1024
#define DINNER 2048
#define NHEADS 32
#define HEADDIM 64
#define DSTATE 128
#define CONVDIM 2304            // DINNER + 2*DSTATE
#define DINPROJ 4384            // 2*DINNER + 2*DSTATE + NHEADS
#define NCLS 48
#define QC 64                   // scan chunk length
#define NCH 8                   // chunks per sequence (SEQLEN/QC)

typedef short bf16x8 __attribute__((ext_vector_type(8)));
typedef float f32x4  __attribute__((ext_vector_type(4)));

static __device__ __forceinline__ unsigned short f2bf(float f) {
    unsigned u = __float_as_uint(f);
    unsigned r = (u + 0x7FFFu + ((u >> 16) & 1u)) >> 16;
    return (unsigned short)r;
}

// ---------------- K0a: inputs fp32 -> bf16 (row-major 1024x1024) -------------
__global__ __launch_bounds__(256) void k_cvt_a(const float* __restrict__ in,
                                               unsigned short* __restrict__ out) {
    int i = (blockIdx.x * 256 + threadIdx.x) * 4;
    float4 v = *(const float4*)(in + i);
    ushort4 o;
    o.x = f2bf(v.x); o.y = f2bf(v.y); o.z = f2bf(v.z); o.w = f2bf(v.w);
    *(ushort4*)(out + i) = o;
}

// ---------------- K0b: W_in (1024x4384) -> Wt bf16 (4384x1024) ---------------
__global__ __launch_bounds__(256) void k_transpose_w(const float* __restrict__ W,
                                                     unsigned short* __restrict__ Wt) {
    __shared__ float tile[32][33];
    int n0 = blockIdx.x * 32;
    int k0 = blockIdx.y * 32;
    int tx = threadIdx.x & 31;
    int ty = threadIdx.x >> 5;
#pragma unroll
    for (int i = 0; i < 4; ++i) {
        int k = k0 + ty + i * 8;
        tile[ty + i * 8][tx] = W[(size_t)k * DINPROJ + n0 + tx];
    }
    __syncthreads();
#pragma unroll
    for (int i = 0; i < 4; ++i) {
        int n = n0 + ty + i * 8;
        Wt[(size_t)n * DMODEL + k0 + tx] = f2bf(tile[tx][ty + i * 8]);
    }
}

// ---------------- K1: zxbcdt = A(1024x1024) @ W(1024x4384), bf16 MFMA --------
__global__ __launch_bounds__(256) void k_gemm_in(const unsigned short* __restrict__ A,
                                                 const unsigned short* __restrict__ Bt,
                                                 float* __restrict__ C) {
    __shared__ unsigned short As[128][40];
    __shared__ unsigned short Bs[64][40];
    const int tid  = threadIdx.x;
    const int m0   = blockIdx.y * 128;
    const int n0   = blockIdx.x * 64;
    const int lr   = tid >> 2;
    const int lc   = (tid & 3) * 8;
    const int wv   = tid >> 6;
    const int lane = tid & 63;
    const int fr   = lane & 15;
    const int fk   = (lane >> 4) * 8;
    f32x4 acc[2][4] = {};
    for (int k0 = 0; k0 < DMODEL; k0 += 32) {
        __syncthreads();
        *(uint4*)(&As[lr][lc])      = *(const uint4*)(A + (size_t)(m0 + lr) * DMODEL + k0 + lc);
        *(uint4*)(&As[lr + 64][lc]) = *(const uint4*)(A + (size_t)(m0 + lr + 64) * DMODEL + k0 + lc);
        int n = n0 + lr;
        uint4 bv = make_uint4(0u, 0u, 0u, 0u);
        if (n < DINPROJ) bv = *(const uint4*)(Bt + (size_t)n * DMODEL + k0 + lc);
        *(uint4*)(&Bs[lr][lc]) = bv;
        __syncthreads();
        bf16x8 af0 = *(const bf16x8*)(&As[wv * 32 + fr][fk]);
        bf16x8 af1 = *(const bf16x8*)(&As[wv * 32 + 16 + fr][fk]);
        bf16x8 bfr[4];
#pragma unroll
        for (int nt = 0; nt < 4; ++nt) bfr[nt] = *(const bf16x8*)(&Bs[nt * 16 + fr][fk]);
#pragma unroll
        for (int nt = 0; nt < 4; ++nt) {
            acc[0][nt] = __builtin_amdgcn_mfma_f32_16x16x32_bf16(af0, bfr[nt], acc[0][nt], 0, 0, 0);
            acc[1][nt] = __builtin_amdgcn_mfma_f32_16x16x32_bf16(af1, bfr[nt], acc[1][nt], 0, 0, 0);
        }
    }
    const int r4 = (lane >> 4) * 4;
#pragma unroll
    for (int mt = 0; mt < 2; ++mt) {
#pragma unroll
        for (int nt = 0; nt < 4; ++nt) {
            int col = n0 + nt * 16 + fr;
            if (col < DINPROJ) {
#pragma unroll
                for (int r = 0; r < 4; ++r) {
                    int row = m0 + wv * 32 + mt * 16 + r4 + r;
                    C[(size_t)row * DINPROJ + col] = acc[mt][nt][r];
                }
            }
        }
    }
}

// ---------------- K2: causal depthwise conv + silu, and dt ------------------
__global__ __launch_bounds__(256) void k_conv_dt(const float* __restrict__ zx,
                                                 const float* __restrict__ conv_w,
                                                 const float* __restrict__ conv_b,
                                                 const float* __restrict__ dt_bias,
                                                 float* __restrict__ xbc,
                                                 float* __restrict__ dtb) {
    int row = blockIdx.y;                 // b*512 + l
    int c   = blockIdx.x * 256 + threadIdx.x;
    int b = row >> 9, l = row & 511;
    if (c < CONVDIM) {
        float acc = conv_b[c];
#pragma unroll
        for (int j = 0; j < 4; ++j) {
            int ls = l - 3 + j;
            float v = (ls >= 0) ? zx[((size_t)(b * SEQLEN + ls)) * DINPROJ + DINNER + c] : 0.f;
            acc += v * conv_w[c * 4 + j];
        }
        float s = acc / (1.f + expf(-acc));
        xbc[(size_t)row * CONVDIM + c] = s;
    } else if (c < CONVDIM + NHEADS) {
        int h = c - CONVDIM;
        float raw = zx[(size_t)row * DINPROJ + (DINNER + CONVDIM) + h] + dt_bias[h];
        float dt = (raw > 20.f) ? raw : log1pf(expf(raw));
        dtb[row * NHEADS + h] = dt;
    }
}

// ---------------- K3a: chunked SSD, intra-chunk (Y_intra + chunk state) ------
// One WG (256 thr = 4 waves) per (b,h,chunk). Q=64.
// G[t,s] = C[t]·B[s] (K=128); G'[t,s] = G * exp(cum[t]-cum[s]) * dt[s], s<=t
// Y_intra = G' @ X ; S_c[p,n] = sum_s x[s,p] * w[s] * B[s,n], w[s]=exp(cumQ-cum[s])*dt[s]
__global__ __launch_bounds__(256) void k_chunk(const float* __restrict__ xbc,
                                               const float* __restrict__ dtb,
                                               const float* __restrict__ A_log,
                                               const float* __restrict__ Dvec,
                                               float* __restrict__ yb,
                                               float* __restrict__ Sc_g,
                                               float* __restrict__ lam_g,
                                               float* __restrict__ esc_g) {
    const int gid = blockIdx.x;           // 0..511
    const int c = gid & 7;
    const int h = (gid >> 3) & 31;
    const int b = gid >> 8;
    const int row0 = b * SEQLEN + c * QC;

    __shared__ float cumS[QC], wS[QC], dtS[QC];
    __shared__ unsigned short Xt[QC][72];        // [p][s]
    __shared__ unsigned short Bs[QC][136];       // [s][n]
    __shared__ unsigned short BtW[DSTATE][72];   // [n][s], weighted by w[s]
    __shared__ unsigned short Cs[QC][136];       // [t][n]
    __shared__ unsigned short Gs[QC][72];        // [t][s], masked+decayed

    const int tid = threadIdx.x;
    // phase 0: wave 0 computes inclusive log-decay cumsum over the chunk
    if (tid < 64) {
        float dtv = dtb[(size_t)(row0 + tid) * NHEADS + h];
        float nA = -expf(A_log[h]);
        float x = dtv * nA;
#pragma unroll
        for (int off = 1; off < 64; off <<= 1) {
            float v = __shfl_up(x, off, 64);
            if (tid >= off) x += v;
        }
        float cumTot = __shfl(x, 63, 64);
        cumS[tid] = x;
        dtS[tid] = dtv;
        wS[tid] = expf(cumTot - x) * dtv;
        esc_g[(size_t)gid * QC + tid] = expf(x);
        if (tid == 0) lam_g[gid] = expf(cumTot);
    }
    __syncthreads();

    // phase 1: stage X^T, B, B^T(weighted), C into LDS as bf16
    {
        int row = tid >> 2;       // s / t index 0..63
        int g = tid & 3;
        const float* rp = xbc + (size_t)(row0 + row) * CONVDIM;
        float wrow = wS[row];
#pragma unroll
        for (int i = 0; i < 4; ++i) {
            float4 v = *(const float4*)(rp + h * HEADDIM + g * 16 + i * 4);
            int p = g * 16 + i * 4;
            Xt[p + 0][row] = f2bf(v.x);
            Xt[p + 1][row] = f2bf(v.y);
            Xt[p + 2][row] = f2bf(v.z);
            Xt[p + 3][row] = f2bf(v.w);
        }
#pragma unroll
        for (int i = 0; i < 8; ++i) {
            int n = g * 32 + i * 4;
            float4 v = *(const float4*)(rp + DINNER + n);
            ushort4 u;
            u.x = f2bf(v.x); u.y = f2bf(v.y); u.z = f2bf(v.z); u.w = f2bf(v.w);
            *(ushort4*)(&Bs[row][n]) = u;
            BtW[n + 0][row] = f2bf(v.x * wrow);
            BtW[n + 1][row] = f2bf(v.y * wrow);
            BtW[n + 2][row] = f2bf(v.z * wrow);
            BtW[n + 3][row] = f2bf(v.w * wrow);
        }
#pragma unroll
        for (int i = 0; i < 8; ++i) {
            int n = g * 32 + i * 4;
            float4 v = *(const float4*)(rp + DINNER + DSTATE + n);
            ushort4 u;
            u.x = f2bf(v.x); u.y = f2bf(v.y); u.z = f2bf(v.z); u.w = f2bf(v.w);
            *(ushort4*)(&Cs[row][n]) = u;
        }
    }
    __syncthreads();

    const int w = tid >> 6, lane = tid & 63;
    const int fr = lane & 15, fq = lane >> 4, fk = (lane >> 4) * 8;

    // GEMM1: G[t,s] = sum_n C[t,n]*B[s,n]; wave w owns t in [w*16, w*16+16)
    f32x4 accG[4] = {};
#pragma unroll
    for (int kk = 0; kk < 4; ++kk) {
        bf16x8 a = *(const bf16x8*)(&Cs[w * 16 + fr][kk * 32 + fk]);
#pragma unroll
        for (int nt = 0; nt < 4; ++nt) {
            bf16x8 bb = *(const bf16x8*)(&Bs[nt * 16 + fr][kk * 32 + fk]);
            accG[nt] = __builtin_amdgcn_mfma_f32_16x16x32_bf16(a, bb, accG[nt], 0, 0, 0);
        }
    }
    // causal mask + decay -> Gs (bf16)
#pragma unroll
    for (int nt = 0; nt < 4; ++nt) {
        int s = nt * 16 + fr;
        float cs = cumS[s], dts = dtS[s];
#pragma unroll
        for (int r = 0; r < 4; ++r) {
            int t = w * 16 + fq * 4 + r;
            float val = (s <= t) ? accG[nt][r] * expf(cumS[t] - cs) * dts : 0.f;
            Gs[t][s] = f2bf(val);
        }
    }
    __syncthreads();

    // GEMM2: Y_intra[t,p] = sum_s Gs[t,s]*Xt[p,s]
    f32x4 accY[4] = {};
#pragma unroll
    for (int kk = 0; kk < 2; ++kk) {
        bf16x8 a = *(const bf16x8*)(&Gs[w * 16 + fr][kk * 32 + fk]);
#pragma unroll
        for (int pt = 0; pt < 4; ++pt) {
            bf16x8 bb = *(const bf16x8*)(&Xt[pt * 16 + fr][kk * 32 + fk]);
            accY[pt] = __builtin_amdgcn_mfma_f32_16x16x32_bf16(a, bb, accY[pt], 0, 0, 0);
        }
    }
    // GEMM3: S_c[p,n] = sum_s Xt[p,s]*BtW[n,s]; wave w owns p in [w*16, ...)
    f32x4 accS[8] = {};
#pragma unroll
    for (int kk = 0; kk < 2; ++kk) {
        bf16x8 a = *(const bf16x8*)(&Xt[w * 16 + fr][kk * 32 + fk]);
#pragma unroll
        for (int nt = 0; nt < 8; ++nt) {
            bf16x8 bb = *(const bf16x8*)(&BtW[nt * 16 + fr][kk * 32 + fk]);
            accS[nt] = __builtin_amdgcn_mfma_f32_16x16x32_bf16(a, bb, accS[nt], 0, 0, 0);
        }
    }
    // write Y_intra + D*x (fp32 x reload for accuracy)
    float Dh = Dvec[h];
#pragma unroll
    for (int pt = 0; pt < 4; ++pt) {
        int p = pt * 16 + fr;
#pragma unroll
        for (int r = 0; r < 4; ++r) {
            int t = w * 16 + fq * 4 + r;
            float xv = xbc[(size_t)(row0 + t) * CONVDIM + h * HEADDIM + p];
            yb[(size_t)(row0 + t) * DINNER + h * HEADDIM + p] = accY[pt][r] + Dh * xv;
        }
    }
    // write chunk state
    float* scp = Sc_g + (size_t)gid * (HEADDIM * DSTATE);
#pragma unroll
    for (int nt = 0; nt < 8; ++nt) {
        int n = nt * 16 + fr;
#pragma unroll
        for (int r = 0; r < 4; ++r) {
            int p = w * 16 + fq * 4 + r;
            scp[p * DSTATE + n] = accS[nt][r];
        }
    }
}

// ---------------- K3b: inter-chunk state chain (sequential over 8 chunks) ----
// One WG per (b,h). S_in[c] = Lam[c-1]*S_in[c-1] + S_c[c-1]; stored as bf16.
__global__ __launch_bounds__(256) void k_chain(const float* __restrict__ Sc_g,
                                               const float* __restrict__ lam_g,
                                               unsigned short* __restrict__ Sin_bf) {
    int bh = blockIdx.x;           // 0..63
    int tid = threadIdx.x;
    float s[32];
#pragma unroll
    for (int i = 0; i < 32; ++i) s[i] = 0.f;
    for (int c = 0; c < NCH; ++c) {
        size_t base = (size_t)(bh * NCH + c) * (HEADDIM * DSTATE) + tid * 32;
        // store S_in for chunk c (state BEFORE chunk c)
#pragma unroll
        for (int j = 0; j < 32; j += 4) {
            ushort4 u;
            u.x = f2bf(s[j + 0]); u.y = f2bf(s[j + 1]);
            u.z = f2bf(s[j + 2]); u.w = f2bf(s[j + 3]);
            *(ushort4*)(Sin_bf + base + j) = u;
        }
        float lam = lam_g[bh * NCH + c];
#pragma unroll
        for (int j = 0; j < 32; j += 4) {
            float4 v = *(const float4*)(Sc_g + base + j);
            s[j + 0] = s[j + 0] * lam + v.x;
            s[j + 1] = s[j + 1] * lam + v.y;
            s[j + 2] = s[j + 2] * lam + v.z;
            s[j + 3] = s[j + 3] * lam + v.w;
        }
    }
}

// ---------------- K3c: cross-chunk term: Y += exp(cum[t]) * C_t · S_in -------
__global__ __launch_bounds__(256) void k_cross(const float* __restrict__ xbc,
                                               const float* __restrict__ esc_g,
                                               const unsigned short* __restrict__ Sin_bf,
                                               float* __restrict__ yb) {
    const int gid = blockIdx.x;
    const int c = gid & 7;
    const int h = (gid >> 3) & 31;
    const int b = gid >> 8;
    const int row0 = b * SEQLEN + c * QC;
    __shared__ unsigned short Ct[QC][136];   // [t][n], scaled by esc[t]
    __shared__ unsigned short Ss[QC][136];   // [p][n]
    const int tid = threadIdx.x;
    {
        int row = tid >> 2, g = tid & 3;
        const float* rp = xbc + (size_t)(row0 + row) * CONVDIM + DINNER + DSTATE;
        float esc = esc_g[(size_t)gid * QC + row];
#pragma unroll
        for (int i = 0; i < 8; ++i) {
            int n = g * 32 + i * 4;
            float4 v = *(const float4*)(rp + n);
            ushort4 u;
            u.x = f2bf(v.x * esc); u.y = f2bf(v.y * esc);
            u.z = f2bf(v.z * esc); u.w = f2bf(v.w * esc);
            *(ushort4*)(&Ct[row][n]) = u;
        }
        const uint4* sp = (const uint4*)(Sin_bf + (size_t)gid * (HEADDIM * DSTATE));
#pragma unroll
        for (int i = 0; i < 4; ++i) {
            uint4 v = sp[row * 16 + g * 4 + i];
            *(uint4*)(&Ss[row][g * 32 + i * 8]) = v;
        }
    }
    __syncthreads();
    const int w = tid >> 6, lane = tid & 63;
    const int fr = lane & 15, fq = lane >> 4, fk = (lane >> 4) * 8;
    f32x4 acc[4] = {};
#pragma unroll
    for (int kk = 0; kk < 4; ++kk) {
        bf16x8 a = *(const bf16x8*)(&Ct[w * 16 + fr][kk * 32 + fk]);
#pragma unroll
        for (int pt = 0; pt < 4; ++pt) {
            bf16x8 bb = *(const bf16x8*)(&Ss[pt * 16 + fr][kk * 32 + fk]);
            acc[pt] = __builtin_amdgcn_mfma_f32_16x16x32_bf16(a, bb, acc[pt], 0, 0, 0);
        }
    }
#pragma unroll
    for (int pt = 0; pt < 4; ++pt) {
        int p = pt * 16 + fr;
#pragma unroll
        for (int r = 0; r < 4; ++r) {
            int t = w * 16 + fq * 4 + r;
            size_t yi = (size_t)(row0 + t) * DINNER + h * HEADDIM + p;
            yb[yi] += acc[pt][r];
        }
    }
}

// ---------------- K4a: gated RMSNorm (in-place over y) -----------------------
__global__ __launch_bounds__(256) void k_gate_norm(const float* __restrict__ zx,
                                                   const float* __restrict__ nw,
                                                   float* __restrict__ y) {
    int row = blockIdx.x;
    int tid = threadIdx.x;
    const float* zrow = zx + (size_t)row * DINPROJ;   // z = cols [0,2048)
    float* yr = y + (size_t)row * DINNER;
    float g[8];
    float ss = 0.f;
#pragma unroll
    for (int i = 0; i < 2; ++i) {
        int c = tid * 4 + i * 1024;
        float4 yv = *(const float4*)(yr + c);
        float4 zv = *(const float4*)(zrow + c);
        float zs[4] = {zv.x, zv.y, zv.z, zv.w};
        float ys[4] = {yv.x, yv.y, yv.z, yv.w};
#pragma unroll
        for (int k = 0; k < 4; ++k) {
            float sil = zs[k] / (1.f + expf(-zs[k]));
            float gg = ys[k] * sil;
            g[i * 4 + k] = gg;
            ss += gg * gg;
        }
    }
#pragma unroll
    for (int off = 32; off >= 1; off >>= 1) ss += __shfl_xor(ss, off, 64);
    __shared__ float wsum[4];
    if ((tid & 63) == 0) wsum[tid >> 6] = ss;
    __syncthreads();
    float tot = wsum[0] + wsum[1] + wsum[2] + wsum[3];
    float scale = rsqrtf(tot / (float)DINNER + 1e-5f);
#pragma unroll
    for (int i = 0; i < 2; ++i) {
        int c = tid * 4 + i * 1024;
        float4 nv = *(const float4*)(nw + c);
        float4 o;
        o.x = g[i * 4 + 0] * scale * nv.x;
        o.y = g[i * 4 + 1] * scale * nv.y;
        o.z = g[i * 4 + 2] * scale * nv.z;
        o.w = g[i * 4 + 3] * scale * nv.w;
        *(float4*)(yr + c) = o;
    }
}

// ---------------- K4b: classifier: out = G @ W_cls + b -----------------------
__global__ __launch_bounds__(64) void k_cls(const float* __restrict__ G,
                                            const float* __restrict__ W,
                                            const float* __restrict__ bcls,
                                            float* __restrict__ out) {
    int r0 = blockIdx.x * 2;
    int j  = threadIdx.x;
    int jj = j < NCLS ? j : NCLS - 1;
    const float* g0 = G + (size_t)r0 * DINNER;
    const float* g1 = g0 + DINNER;
    float a0 = 0.f, a1 = 0.f;
    for (int k = 0; k < DINNER; ++k) {
        float wv = W[(size_t)k * NCLS + jj];
        a0 += g0[k] * wv;
        a1 += g1[k] * wv;
    }
    if (j < NCLS) {
        float bb = bcls[j];
        out[(size_t)r0 * NCLS + j]        = a0 + bb;
        out[(size_t)(r0 + 1) * NCLS + j]  = a1 + bb;
    }
}

// ---------------- launch -----------------------------------------------------
extern "C" void kernel_launch(void* const* d_in, const int* in_sizes, int n_in,
                              void* d_out, int out_size, void* d_ws, size_t ws_size,
                              hipStream_t stream) {
    const float* inputs  = (const float*)d_in[0];
    const float* W_in    = (const float*)d_in[1];
    const float* conv_w  = (const float*)d_in[2];
    const float* conv_b  = (const float*)d_in[3];
    const float* dt_bias = (const float*)d_in[4];
    const float* A_log   = (const float*)d_in[5];
    const float* Dvec    = (const float*)d_in[6];
    const float* norm_w  = (const float*)d_in[7];
    // d_in[8] = W_out (unused by reference output)
    const float* W_cls   = (const float*)d_in[9];
    const float* b_cls   = (const float*)d_in[10];
    float* out = (float*)d_out;

    // workspace layout (floats first, then ushorts) -- ~72 MB total
    float* ws   = (float*)d_ws;
    float* zx   = ws;                            // BL*4384
    float* xbc  = zx   + (size_t)BL * DINPROJ;   // BL*2304
    float* dtb  = xbc  + (size_t)BL * CONVDIM;   // BL*32
    float* yb   = dtb  + (size_t)BL * NHEADS;    // BL*2048
    float* Sc_g = yb   + (size_t)BL * DINNER;    // 512*8192
    float* lam_g= Sc_g + (size_t)BATCH * NHEADS * NCH * HEADDIM * DSTATE;  // 512
    float* esc_g= lam_g+ (size_t)BATCH * NHEADS * NCH;                     // 512*64
    unsigned short* Sin_bf = (unsigned short*)(esc_g + (size_t)BATCH * NHEADS * NCH * QC);
    unsigned short* abf    = Sin_bf + (size_t)BATCH * NHEADS * NCH * HEADDIM * DSTATE;
    unsigned short* wtbf   = abf + (size_t)BL * DMODEL;

    k_cvt_a<<<dim3(BL * DMODEL / (256 * 4)), dim3(256), 0, stream>>>(inputs, abf);
    k_transpose_w<<<dim3(DINPROJ / 32, DMODEL / 32), dim3(256), 0, stream>>>(W_in, wtbf);
    k_gemm_in<<<dim3((DINPROJ + 63) / 64, BL / 128), dim3(256), 0, stream>>>(abf, wtbf, zx);
    k_conv_dt<<<dim3(10, BL), dim3(256), 0, stream>>>(zx, conv_w, conv_b, dt_bias, xbc, dtb);
    k_chunk<<<dim3(BATCH * NHEADS * NCH), dim3(256), 0, stream>>>(xbc, dtb, A_log, Dvec,
                                                                  yb, Sc_g, lam_g, esc_g);
    k_chain<<<dim3(BATCH * NHEADS), dim3(256), 0, stream>>>(Sc_g, lam_g, Sin_bf);
    k_cross<<<dim3(BATCH * NHEADS * NCH), dim3(256), 0, stream>>>(xbc, esc_g, Sin_bf, yb);
    k_gate_norm<<<dim3(BL), dim3(256), 0, stream>>>(zx, norm_w, yb);
    k_cls<<<dim3(BL / 2), dim3(64), 0, stream>>>(yb, W_cls, b_cls, out);
}

// Round 3
// 191.283 us; speedup vs baseline: 3.0307x; 1.6590x over previous
//
#include <hip/hip_runtime.h>
#include <hip/hip_bf16.h>
#include <cstdint>

// Problem constants
#define BATCH 2
#define SEQLEN 512
#define BL (BATCH*SEQLEN)       // 1024 rows
#define DMODEL 1024
#define DINNER 2048
#define NHEADS 32
#define HEADDIM 64
#define DSTATE 128
#define CONVDIM 2304            // DINNER + 2*DSTATE
#define DINPROJ 4384            // 2*DINNER + 2*DSTATE + NHEADS
#define NCLS 48
#define QC 64                   // scan chunk length
#define NCH 8                   // chunks per sequence (SEQLEN/QC)

typedef short bf16x8 __attribute__((ext_vector_type(8)));
typedef float f32x4  __attribute__((ext_vector_type(4)));

static __device__ __forceinline__ unsigned short f2bf(float f) {
    unsigned u = __float_as_uint(f);
    unsigned r = (u + 0x7FFFu + ((u >> 16) & 1u)) >> 16;
    return (unsigned short)r;
}

// ---------------- K0a: inputs fp32 -> bf16 (row-major 1024x1024) -------------
__global__ __launch_bounds__(256) void k_cvt_a(const float* __restrict__ in,
                                               unsigned short* __restrict__ out) {
    int i = (blockIdx.x * 256 + threadIdx.x) * 4;
    float4 v = *(const float4*)(in + i);
    ushort4 o;
    o.x = f2bf(v.x); o.y = f2bf(v.y); o.z = f2bf(v.z); o.w = f2bf(v.w);
    *(ushort4*)(out + i) = o;
}

// ---------------- K0b: W_in (1024x4384) -> Wt bf16 (4384x1024) ---------------
__global__ __launch_bounds__(256) void k_transpose_w(const float* __restrict__ W,
                                                     unsigned short* __restrict__ Wt) {
    __shared__ float tile[32][33];
    int n0 = blockIdx.x * 32;
    int k0 = blockIdx.y * 32;
    int tx = threadIdx.x & 31;
    int ty = threadIdx.x >> 5;
#pragma unroll
    for (int i = 0; i < 4; ++i) {
        int k = k0 + ty + i * 8;
        tile[ty + i * 8][tx] = W[(size_t)k * DINPROJ + n0 + tx];
    }
    __syncthreads();
#pragma unroll
    for (int i = 0; i < 4; ++i) {
        int n = n0 + ty + i * 8;
        Wt[(size_t)n * DMODEL + k0 + tx] = f2bf(tile[tx][ty + i * 8]);
    }
}

// ---------------- K0c: W_cls (2048x48) -> Wt bf16 (48x2048) ------------------
__global__ __launch_bounds__(256) void k_cvt_wcls(const float* __restrict__ W,
                                                  unsigned short* __restrict__ Wt) {
    int n = blockIdx.x;           // 0..47
    for (int k = threadIdx.x; k < DINNER; k += 256)
        Wt[(size_t)n * DINNER + k] = f2bf(W[(size_t)k * NCLS + n]);
}

// ---------------- K1: zxbcdt = A(1024x1024) @ W(1024x4384), bf16 MFMA --------
__global__ __launch_bounds__(256) void k_gemm_in(const unsigned short* __restrict__ A,
                                                 const unsigned short* __restrict__ Bt,
                                                 float* __restrict__ C) {
    __shared__ unsigned short As[128][40];
    __shared__ unsigned short Bs[64][40];
    const int tid  = threadIdx.x;
    const int m0   = blockIdx.y * 128;
    const int n0   = blockIdx.x * 64;
    const int lr   = tid >> 2;
    const int lc   = (tid & 3) * 8;
    const int wv   = tid >> 6;
    const int lane = tid & 63;
    const int fr   = lane & 15;
    const int fk   = (lane >> 4) * 8;
    f32x4 acc[2][4] = {};
    for (int k0 = 0; k0 < DMODEL; k0 += 32) {
        __syncthreads();
        *(uint4*)(&As[lr][lc])      = *(const uint4*)(A + (size_t)(m0 + lr) * DMODEL + k0 + lc);
        *(uint4*)(&As[lr + 64][lc]) = *(const uint4*)(A + (size_t)(m0 + lr + 64) * DMODEL + k0 + lc);
        int n = n0 + lr;
        uint4 bv = make_uint4(0u, 0u, 0u, 0u);
        if (n < DINPROJ) bv = *(const uint4*)(Bt + (size_t)n * DMODEL + k0 + lc);
        *(uint4*)(&Bs[lr][lc]) = bv;
        __syncthreads();
        bf16x8 af0 = *(const bf16x8*)(&As[wv * 32 + fr][fk]);
        bf16x8 af1 = *(const bf16x8*)(&As[wv * 32 + 16 + fr][fk]);
        bf16x8 bfr[4];
#pragma unroll
        for (int nt = 0; nt < 4; ++nt) bfr[nt] = *(const bf16x8*)(&Bs[nt * 16 + fr][fk]);
#pragma unroll
        for (int nt = 0; nt < 4; ++nt) {
            acc[0][nt] = __builtin_amdgcn_mfma_f32_16x16x32_bf16(af0, bfr[nt], acc[0][nt], 0, 0, 0);
            acc[1][nt] = __builtin_amdgcn_mfma_f32_16x16x32_bf16(af1, bfr[nt], acc[1][nt], 0, 0, 0);
        }
    }
    const int r4 = (lane >> 4) * 4;
#pragma unroll
    for (int mt = 0; mt < 2; ++mt) {
#pragma unroll
        for (int nt = 0; nt < 4; ++nt) {
            int col = n0 + nt * 16 + fr;
            if (col < DINPROJ) {
#pragma unroll
                for (int r = 0; r < 4; ++r) {
                    int row = m0 + wv * 32 + mt * 16 + r4 + r;
                    C[(size_t)row * DINPROJ + col] = acc[mt][nt][r];
                }
            }
        }
    }
}

// ---------------- K2: causal depthwise conv + silu, and dt ------------------
__global__ __launch_bounds__(256) void k_conv_dt(const float* __restrict__ zx,
                                                 const float* __restrict__ conv_w,
                                                 const float* __restrict__ conv_b,
                                                 const float* __restrict__ dt_bias,
                                                 float* __restrict__ xbc,
                                                 float* __restrict__ dtb) {
    int row = blockIdx.y;                 // b*512 + l
    int c   = blockIdx.x * 256 + threadIdx.x;
    int b = row >> 9, l = row & 511;
    if (c < CONVDIM) {
        float acc = conv_b[c];
#pragma unroll
        for (int j = 0; j < 4; ++j) {
            int ls = l - 3 + j;
            float v = (ls >= 0) ? zx[((size_t)(b * SEQLEN + ls)) * DINPROJ + DINNER + c] : 0.f;
            acc += v * conv_w[c * 4 + j];
        }
        float s = acc / (1.f + expf(-acc));
        xbc[(size_t)row * CONVDIM + c] = s;
    } else if (c < CONVDIM + NHEADS) {
        int h = c - CONVDIM;
        float raw = zx[(size_t)row * DINPROJ + (DINNER + CONVDIM) + h] + dt_bias[h];
        float dt = (raw > 20.f) ? raw : log1pf(expf(raw));
        dtb[row * NHEADS + h] = dt;
    }
}

// ---------------- K3a: chunked SSD, intra-chunk (Y_intra + chunk state) ------
__global__ __launch_bounds__(256) void k_chunk(const float* __restrict__ xbc,
                                               const float* __restrict__ dtb,
                                               const float* __restrict__ A_log,
                                               const float* __restrict__ Dvec,
                                               float* __restrict__ yb,
                                               float* __restrict__ Sc_g,
                                               float* __restrict__ lam_g,
                                               float* __restrict__ esc_g) {
    const int gid = blockIdx.x;           // 0..511
    const int c = gid & 7;
    const int h = (gid >> 3) & 31;
    const int b = gid >> 8;
    const int row0 = b * SEQLEN + c * QC;

    __shared__ float cumS[QC], wS[QC], dtS[QC];
    __shared__ unsigned short Xt[QC][72];        // [p][s]
    __shared__ unsigned short Bs[QC][136];       // [s][n]
    __shared__ unsigned short BtW[DSTATE][72];   // [n][s], weighted by w[s]
    __shared__ unsigned short Cs[QC][136];       // [t][n]
    __shared__ unsigned short Gs[QC][72];        // [t][s], masked+decayed

    const int tid = threadIdx.x;
    if (tid < 64) {
        float dtv = dtb[(size_t)(row0 + tid) * NHEADS + h];
        float nA = -expf(A_log[h]);
        float x = dtv * nA;
#pragma unroll
        for (int off = 1; off < 64; off <<= 1) {
            float v = __shfl_up(x, off, 64);
            if (tid >= off) x += v;
        }
        float cumTot = __shfl(x, 63, 64);
        cumS[tid] = x;
        dtS[tid] = dtv;
        wS[tid] = expf(cumTot - x) * dtv;
        esc_g[(size_t)gid * QC + tid] = expf(x);
        if (tid == 0) lam_g[gid] = expf(cumTot);
    }
    __syncthreads();

    {
        int row = tid >> 2;       // s / t index 0..63
        int g = tid & 3;
        const float* rp = xbc + (size_t)(row0 + row) * CONVDIM;
        float wrow = wS[row];
#pragma unroll
        for (int i = 0; i < 4; ++i) {
            float4 v = *(const float4*)(rp + h * HEADDIM + g * 16 + i * 4);
            int p = g * 16 + i * 4;
            Xt[p + 0][row] = f2bf(v.x);
            Xt[p + 1][row] = f2bf(v.y);
            Xt[p + 2][row] = f2bf(v.z);
            Xt[p + 3][row] = f2bf(v.w);
        }
#pragma unroll
        for (int i = 0; i < 8; ++i) {
            int n = g * 32 + i * 4;
            float4 v = *(const float4*)(rp + DINNER + n);
            ushort4 u;
            u.x = f2bf(v.x); u.y = f2bf(v.y); u.z = f2bf(v.z); u.w = f2bf(v.w);
            *(ushort4*)(&Bs[row][n]) = u;
            BtW[n + 0][row] = f2bf(v.x * wrow);
            BtW[n + 1][row] = f2bf(v.y * wrow);
            BtW[n + 2][row] = f2bf(v.z * wrow);
            BtW[n + 3][row] = f2bf(v.w * wrow);
        }
#pragma unroll
        for (int i = 0; i < 8; ++i) {
            int n = g * 32 + i * 4;
            float4 v = *(const float4*)(rp + DINNER + DSTATE + n);
            ushort4 u;
            u.x = f2bf(v.x); u.y = f2bf(v.y); u.z = f2bf(v.z); u.w = f2bf(v.w);
            *(ushort4*)(&Cs[row][n]) = u;
        }
    }
    __syncthreads();

    const int w = tid >> 6, lane = tid & 63;
    const int fr = lane & 15, fq = lane >> 4, fk = (lane >> 4) * 8;

    f32x4 accG[4] = {};
#pragma unroll
    for (int kk = 0; kk < 4; ++kk) {
        bf16x8 a = *(const bf16x8*)(&Cs[w * 16 + fr][kk * 32 + fk]);
#pragma unroll
        for (int nt = 0; nt < 4; ++nt) {
            bf16x8 bb = *(const bf16x8*)(&Bs[nt * 16 + fr][kk * 32 + fk]);
            accG[nt] = __builtin_amdgcn_mfma_f32_16x16x32_bf16(a, bb, accG[nt], 0, 0, 0);
        }
    }
#pragma unroll
    for (int nt = 0; nt < 4; ++nt) {
        int s = nt * 16 + fr;
        float cs = cumS[s], dts = dtS[s];
#pragma unroll
        for (int r = 0; r < 4; ++r) {
            int t = w * 16 + fq * 4 + r;
            float val = (s <= t) ? accG[nt][r] * expf(cumS[t] - cs) * dts : 0.f;
            Gs[t][s] = f2bf(val);
        }
    }
    __syncthreads();

    f32x4 accY[4] = {};
#pragma unroll
    for (int kk = 0; kk < 2; ++kk) {
        bf16x8 a = *(const bf16x8*)(&Gs[w * 16 + fr][kk * 32 + fk]);
#pragma unroll
        for (int pt = 0; pt < 4; ++pt) {
            bf16x8 bb = *(const bf16x8*)(&Xt[pt * 16 + fr][kk * 32 + fk]);
            accY[pt] = __builtin_amdgcn_mfma_f32_16x16x32_bf16(a, bb, accY[pt], 0, 0, 0);
        }
    }
    f32x4 accS[8] = {};
#pragma unroll
    for (int kk = 0; kk < 2; ++kk) {
        bf16x8 a = *(const bf16x8*)(&Xt[w * 16 + fr][kk * 32 + fk]);
#pragma unroll
        for (int nt = 0; nt < 8; ++nt) {
            bf16x8 bb = *(const bf16x8*)(&BtW[nt * 16 + fr][kk * 32 + fk]);
            accS[nt] = __builtin_amdgcn_mfma_f32_16x16x32_bf16(a, bb, accS[nt], 0, 0, 0);
        }
    }
    float Dh = Dvec[h];
#pragma unroll
    for (int pt = 0; pt < 4; ++pt) {
        int p = pt * 16 + fr;
#pragma unroll
        for (int r = 0; r < 4; ++r) {
            int t = w * 16 + fq * 4 + r;
            float xv = xbc[(size_t)(row0 + t) * CONVDIM + h * HEADDIM + p];
            yb[(size_t)(row0 + t) * DINNER + h * HEADDIM + p] = accY[pt][r] + Dh * xv;
        }
    }
    float* scp = Sc_g + (size_t)gid * (HEADDIM * DSTATE);
#pragma unroll
    for (int nt = 0; nt < 8; ++nt) {
        int n = nt * 16 + fr;
#pragma unroll
        for (int r = 0; r < 4; ++r) {
            int p = w * 16 + fq * 4 + r;
            scp[p * DSTATE + n] = accS[nt][r];
        }
    }
}

// ---------------- K3b: inter-chunk state chain (sequential over 8 chunks) ----
__global__ __launch_bounds__(256) void k_chain(const float* __restrict__ Sc_g,
                                               const float* __restrict__ lam_g,
                                               unsigned short* __restrict__ Sin_bf) {
    int bh = blockIdx.x;           // 0..63
    int tid = threadIdx.x;
    float s[32];
#pragma unroll
    for (int i = 0; i < 32; ++i) s[i] = 0.f;
    for (int c = 0; c < NCH; ++c) {
        size_t base = (size_t)(bh * NCH + c) * (HEADDIM * DSTATE) + tid * 32;
#pragma unroll
        for (int j = 0; j < 32; j += 4) {
            ushort4 u;
            u.x = f2bf(s[j + 0]); u.y = f2bf(s[j + 1]);
            u.z = f2bf(s[j + 2]); u.w = f2bf(s[j + 3]);
            *(ushort4*)(Sin_bf + base + j) = u;
        }
        float lam = lam_g[bh * NCH + c];
#pragma unroll
        for (int j = 0; j < 32; j += 4) {
            float4 v = *(const float4*)(Sc_g + base + j);
            s[j + 0] = s[j + 0] * lam + v.x;
            s[j + 1] = s[j + 1] * lam + v.y;
            s[j + 2] = s[j + 2] * lam + v.z;
            s[j + 3] = s[j + 3] * lam + v.w;
        }
    }
}

// ---------------- K3c: cross-chunk term: Y += exp(cum[t]) * C_t · S_in -------
__global__ __launch_bounds__(256) void k_cross(const float* __restrict__ xbc,
                                               const float* __restrict__ esc_g,
                                               const unsigned short* __restrict__ Sin_bf,
                                               float* __restrict__ yb) {
    const int gid = blockIdx.x;
    const int c = gid & 7;
    const int h = (gid >> 3) & 31;
    const int b = gid >> 8;
    const int row0 = b * SEQLEN + c * QC;
    __shared__ unsigned short Ct[QC][136];   // [t][n], scaled by esc[t]
    __shared__ unsigned short Ss[QC][136];   // [p][n]
    const int tid = threadIdx.x;
    {
        int row = tid >> 2, g = tid & 3;
        const float* rp = xbc + (size_t)(row0 + row) * CONVDIM + DINNER + DSTATE;
        float esc = esc_g[(size_t)gid * QC + row];
#pragma unroll
        for (int i = 0; i < 8; ++i) {
            int n = g * 32 + i * 4;
            float4 v = *(const float4*)(rp + n);
            ushort4 u;
            u.x = f2bf(v.x * esc); u.y = f2bf(v.y * esc);
            u.z = f2bf(v.z * esc); u.w = f2bf(v.w * esc);
            *(ushort4*)(&Ct[row][n]) = u;
        }
        const uint4* sp = (const uint4*)(Sin_bf + (size_t)gid * (HEADDIM * DSTATE));
#pragma unroll
        for (int i = 0; i < 4; ++i) {
            uint4 v = sp[row * 16 + g * 4 + i];
            *(uint4*)(&Ss[row][g * 32 + i * 8]) = v;
        }
    }
    __syncthreads();
    const int w = tid >> 6, lane = tid & 63;
    const int fr = lane & 15, fq = lane >> 4, fk = (lane >> 4) * 8;
    f32x4 acc[4] = {};
#pragma unroll
    for (int kk = 0; kk < 4; ++kk) {
        bf16x8 a = *(const bf16x8*)(&Ct[w * 16 + fr][kk * 32 + fk]);
#pragma unroll
        for (int pt = 0; pt < 4; ++pt) {
            bf16x8 bb = *(const bf16x8*)(&Ss[pt * 16 + fr][kk * 32 + fk]);
            acc[pt] = __builtin_amdgcn_mfma_f32_16x16x32_bf16(a, bb, acc[pt], 0, 0, 0);
        }
    }
#pragma unroll
    for (int pt = 0; pt < 4; ++pt) {
        int p = pt * 16 + fr;
#pragma unroll
        for (int r = 0; r < 4; ++r) {
            int t = w * 16 + fq * 4 + r;
            size_t yi = (size_t)(row0 + t) * DINNER + h * HEADDIM + p;
            yb[yi] += acc[pt][r];
        }
    }
}

// ---------------- K4a: gated RMSNorm -> bf16 G -------------------------------
__global__ __launch_bounds__(256) void k_gate_norm(const float* __restrict__ zx,
                                                   const float* __restrict__ nw,
                                                   const float* __restrict__ y,
                                                   unsigned short* __restrict__ Gbf) {
    int row = blockIdx.x;
    int tid = threadIdx.x;
    const float* zrow = zx + (size_t)row * DINPROJ;   // z = cols [0,2048)
    const float* yr = y + (size_t)row * DINNER;
    float g[8];
    float ss = 0.f;
#pragma unroll
    for (int i = 0; i < 2; ++i) {
        int c = tid * 4 + i * 1024;
        float4 yv = *(const float4*)(yr + c);
        float4 zv = *(const float4*)(zrow + c);
        float zs[4] = {zv.x, zv.y, zv.z, zv.w};
        float ys[4] = {yv.x, yv.y, yv.z, yv.w};
#pragma unroll
        for (int k = 0; k < 4; ++k) {
            float sil = zs[k] / (1.f + expf(-zs[k]));
            float gg = ys[k] * sil;
            g[i * 4 + k] = gg;
            ss += gg * gg;
        }
    }
#pragma unroll
    for (int off = 32; off >= 1; off >>= 1) ss += __shfl_xor(ss, off, 64);
    __shared__ float wsum[4];
    if ((tid & 63) == 0) wsum[tid >> 6] = ss;
    __syncthreads();
    float tot = wsum[0] + wsum[1] + wsum[2] + wsum[3];
    float scale = rsqrtf(tot / (float)DINNER + 1e-5f);
#pragma unroll
    for (int i = 0; i < 2; ++i) {
        int c = tid * 4 + i * 1024;
        float4 nv = *(const float4*)(nw + c);
        ushort4 o;
        o.x = f2bf(g[i * 4 + 0] * scale * nv.x);
        o.y = f2bf(g[i * 4 + 1] * scale * nv.y);
        o.z = f2bf(g[i * 4 + 2] * scale * nv.z);
        o.w = f2bf(g[i * 4 + 3] * scale * nv.w);
        *(ushort4*)(Gbf + (size_t)row * DINNER + c) = o;
    }
}

// ---------------- K4b0: out init with bias -----------------------------------
__global__ __launch_bounds__(256) void k_init_out(const float* __restrict__ bcls,
                                                  float* __restrict__ out) {
    int i = blockIdx.x * 256 + threadIdx.x;   // < 1024*48
    out[i] = bcls[i % NCLS];
}

// ---------------- K4b: classifier GEMM (split-K, MFMA, atomicAdd) ------------
// G (1024x2048 bf16) @ Wt^T (Wt is 48x2048 bf16) -> out (1024x48 fp32)
// grid (M/64, 8): BM=64, BN=48, BK=256; 4 waves, wave w owns rows [w*16,+16)
__global__ __launch_bounds__(256) void k_cls_mfma(const unsigned short* __restrict__ G,
                                                  const unsigned short* __restrict__ Wt,
                                                  float* __restrict__ out) {
    __shared__ unsigned short Gs[64][72];
    __shared__ unsigned short Ws[48][72];
    const int m0  = blockIdx.x * 64;
    const int k00 = blockIdx.y * 256;
    const int tid = threadIdx.x;
    const int w = tid >> 6, lane = tid & 63;
    const int fr = lane & 15, fq = lane >> 4, fk = fq * 8;
    f32x4 acc[3] = {};
    for (int ks = 0; ks < 4; ++ks) {
        int k0 = k00 + ks * 64;
        __syncthreads();
        {
            int row = tid >> 2, seg = (tid & 3) * 16;
            const unsigned short* gp = G + (size_t)(m0 + row) * DINNER + k0 + seg;
            *(uint4*)(&Gs[row][seg])     = *(const uint4*)(gp);
            *(uint4*)(&Gs[row][seg + 8]) = *(const uint4*)(gp + 8);
        }
        if (tid < 192) {
            int row = tid >> 2, seg = (tid & 3) * 16;
            const unsigned short* wp = Wt + (size_t)row * DINNER + k0 + seg;
            *(uint4*)(&Ws[row][seg])     = *(const uint4*)(wp);
            *(uint4*)(&Ws[row][seg + 8]) = *(const uint4*)(wp + 8);
        }
        __syncthreads();
#pragma unroll
        for (int kk = 0; kk < 2; ++kk) {
            bf16x8 a = *(const bf16x8*)(&Gs[w * 16 + fr][kk * 32 + fk]);
#pragma unroll
            for (int nt = 0; nt < 3; ++nt) {
                bf16x8 bb = *(const bf16x8*)(&Ws[nt * 16 + fr][kk * 32 + fk]);
                acc[nt] = __builtin_amdgcn_mfma_f32_16x16x32_bf16(a, bb, acc[nt], 0, 0, 0);
            }
        }
    }
#pragma unroll
    for (int nt = 0; nt < 3; ++nt) {
        int col = nt * 16 + fr;
#pragma unroll
        for (int r = 0; r < 4; ++r) {
            int row = m0 + w * 16 + fq * 4 + r;
            atomicAdd(&out[(size_t)row * NCLS + col], acc[nt][r]);
        }
    }
}

// ---------------- launch -----------------------------------------------------
extern "C" void kernel_launch(void* const* d_in, const int* in_sizes, int n_in,
                              void* d_out, int out_size, void* d_ws, size_t ws_size,
                              hipStream_t stream) {
    const float* inputs  = (const float*)d_in[0];
    const float* W_in    = (const float*)d_in[1];
    const float* conv_w  = (const float*)d_in[2];
    const float* conv_b  = (const float*)d_in[3];
    const float* dt_bias = (const float*)d_in[4];
    const float* A_log   = (const float*)d_in[5];
    const float* Dvec    = (const float*)d_in[6];
    const float* norm_w  = (const float*)d_in[7];
    // d_in[8] = W_out (unused by reference output)
    const float* W_cls   = (const float*)d_in[9];
    const float* b_cls   = (const float*)d_in[10];
    float* out = (float*)d_out;

    // workspace layout
    float* ws   = (float*)d_ws;
    float* zx   = ws;                            // BL*4384
    float* xbc  = zx   + (size_t)BL * DINPROJ;   // BL*2304
    float* dtb  = xbc  + (size_t)BL * CONVDIM;   // BL*32
    float* yb   = dtb  + (size_t)BL * NHEADS;    // BL*2048
    float* Sc_g = yb   + (size_t)BL * DINNER;    // 512*8192 (dead after k_chain; Gbf aliases it)
    float* lam_g= Sc_g + (size_t)BATCH * NHEADS * NCH * HEADDIM * DSTATE;  // 512
    float* esc_g= lam_g+ (size_t)BATCH * NHEADS * NCH;                     // 512*64
    unsigned short* Sin_bf = (unsigned short*)(esc_g + (size_t)BATCH * NHEADS * NCH * QC);
    unsigned short* abf    = Sin_bf + (size_t)BATCH * NHEADS * NCH * HEADDIM * DSTATE;
    unsigned short* wtbf   = abf + (size_t)BL * DMODEL;                    // 4384*1024
    unsigned short* wclsbf = wtbf + (size_t)DINPROJ * DMODEL;              // 48*2048
    unsigned short* Gbf    = (unsigned short*)Sc_g;  // alias: Sc_g is dead post-k_chain

    k_cvt_a<<<dim3(BL * DMODEL / (256 * 4)), dim3(256), 0, stream>>>(inputs, abf);
    k_transpose_w<<<dim3(DINPROJ / 32, DMODEL / 32), dim3(256), 0, stream>>>(W_in, wtbf);
    k_cvt_wcls<<<dim3(NCLS), dim3(256), 0, stream>>>(W_cls, wclsbf);
    k_gemm_in<<<dim3((DINPROJ + 63) / 64, BL / 128), dim3(256), 0, stream>>>(abf, wtbf, zx);
    k_conv_dt<<<dim3(10, BL), dim3(256), 0, stream>>>(zx, conv_w, conv_b, dt_bias, xbc, dtb);
    k_chunk<<<dim3(BATCH * NHEADS * NCH), dim3(256), 0, stream>>>(xbc, dtb, A_log, Dvec,
                                                                  yb, Sc_g, lam_g, esc_g);
    k_chain<<<dim3(BATCH * NHEADS), dim3(256), 0, stream>>>(Sc_g, lam_g, Sin_bf);
    k_cross<<<dim3(BATCH * NHEADS * NCH), dim3(256), 0, stream>>>(xbc, esc_g, Sin_bf, yb);
    k_gate_norm<<<dim3(BL), dim3(256), 0, stream>>>(zx, norm_w, yb, Gbf);
    k_init_out<<<dim3(BL * NCLS / 256), dim3(256), 0, stream>>>(b_cls, out);
    k_cls_mfma<<<dim3(BL / 64, 8), dim3(256), 0, stream>>>(Gbf, wclsbf, out);
}

// Round 4
// 184.130 us; speedup vs baseline: 3.1484x; 1.0388x over previous
//
#include <hip/hip_runtime.h>
#include <hip/hip_bf16.h>
#include <cstdint>

// Problem constants
#define BATCH 2
#define SEQLEN 512
#define BL (BATCH*SEQLEN)       // 1024 rows
#define DMODEL 1024
#define DINNER 2048
#define NHEADS 32
#define HEADDIM 64
#define DSTATE 128
#define CONVDIM 2304            // DINNER + 2*DSTATE
#define DINPROJ 4384            // 2*DINNER + 2*DSTATE + NHEADS
#define NPROJPAD 4480           // DINPROJ padded to 128 multiple (DMA-safe N tail)
#define NCLS 48
#define QC 64                   // scan chunk length
#define NCH 8                   // chunks per sequence (SEQLEN/QC)

typedef short bf16x8 __attribute__((ext_vector_type(8)));
typedef float f32x4  __attribute__((ext_vector_type(4)));
typedef unsigned int u32;
typedef const __attribute__((address_space(1))) u32 gu32;
typedef __attribute__((address_space(3))) u32 lu32;

static __device__ __forceinline__ void gl16(const void* g, void* l) {
    // async global->LDS DMA, 16B/lane; LDS dest = wave-uniform base + lane*16
    __builtin_amdgcn_global_load_lds((gu32*)g, (lu32*)l, 16, 0, 0);
}

static __device__ __forceinline__ unsigned short f2bf(float f) {
    unsigned u = __float_as_uint(f);
    unsigned r = (u + 0x7FFFu + ((u >> 16) & 1u)) >> 16;
    return (unsigned short)r;
}

// ---------------- K0a: inputs fp32 -> bf16 (row-major 1024x1024) -------------
__global__ __launch_bounds__(256) void k_cvt_a(const float* __restrict__ in,
                                               unsigned short* __restrict__ out) {
    int i = (blockIdx.x * 256 + threadIdx.x) * 4;
    float4 v = *(const float4*)(in + i);
    ushort4 o;
    o.x = f2bf(v.x); o.y = f2bf(v.y); o.z = f2bf(v.z); o.w = f2bf(v.w);
    *(ushort4*)(out + i) = o;
}

// ---------------- K0b: W_in (1024x4384) -> Wt bf16 (4384x1024) ---------------
__global__ __launch_bounds__(256) void k_transpose_w(const float* __restrict__ W,
                                                     unsigned short* __restrict__ Wt) {
    __shared__ float tile[32][33];
    int n0 = blockIdx.x * 32;
    int k0 = blockIdx.y * 32;
    int tx = threadIdx.x & 31;
    int ty = threadIdx.x >> 5;
#pragma unroll
    for (int i = 0; i < 4; ++i) {
        int k = k0 + ty + i * 8;
        tile[ty + i * 8][tx] = W[(size_t)k * DINPROJ + n0 + tx];
    }
    __syncthreads();
#pragma unroll
    for (int i = 0; i < 4; ++i) {
        int n = n0 + ty + i * 8;
        Wt[(size_t)n * DMODEL + k0 + tx] = f2bf(tile[tx][ty + i * 8]);
    }
}

// ---------------- K0c: classifier prep: out=bias broadcast + W_cls^T bf16 ----
__global__ __launch_bounds__(256) void k_prep_cls(const float* __restrict__ W,
                                                  const float* __restrict__ bcls,
                                                  unsigned short* __restrict__ Wt,
                                                  float* __restrict__ out) {
    int bid = blockIdx.x;
    if (bid < 192) {                       // 192*256 = 1024*48
        int i = bid * 256 + threadIdx.x;
        out[i] = bcls[i % NCLS];
    } else {
        int n = bid - 192;                 // 0..47
        for (int k = threadIdx.x; k < DINNER; k += 256)
            Wt[(size_t)n * DINNER + k] = f2bf(W[(size_t)k * NCLS + n]);
    }
}

// ---------------- K1: zxbcdt = A(1024x1024) @ W(1024x4384), bf16 MFMA --------
// m97-style: 128x128 tile, BK=32, global_load_lds width=16, 4 waves in 2x2,
// each wave computes 64x64 via 4x4 frags of 16x16x32.
__global__ __launch_bounds__(256) void k_gemm_in(const unsigned short* __restrict__ A,
                                                 const unsigned short* __restrict__ Bt,
                                                 float* __restrict__ C) {
    __shared__ unsigned short As[128 * 32];   // row-major [128][32], unpadded (DMA layout)
    __shared__ unsigned short Bs[128 * 32];
    const int tid  = threadIdx.x;
    const int m0   = blockIdx.y * 128;
    const int n0   = blockIdx.x * 128;
    const int w    = tid >> 6;            // wave 0..3
    const int lane = tid & 63;
    const int wm   = w >> 1, wn = w & 1;
    const int fr   = lane & 15, fq = lane >> 4;
    // staging: wave w handles rows [w*16,+16) (chunk 0) and [64+w*16,+16) (chunk 1)
    const int srow = w * 16 + (lane >> 2);
    const int skg  = (lane & 3) * 8;      // k-offset in ushorts
    const unsigned short* gA0 = A  + (size_t)(m0 + srow) * DMODEL + skg;
    const unsigned short* gA1 = gA0 + (size_t)64 * DMODEL;
    const unsigned short* gB0 = Bt + (size_t)(n0 + srow) * DMODEL + skg;
    const unsigned short* gB1 = gB0 + (size_t)64 * DMODEL;
    unsigned short* lA0 = As + w * 512;          // uniform per wave
    unsigned short* lA1 = As + 2048 + w * 512;
    unsigned short* lB0 = Bs + w * 512;
    unsigned short* lB1 = Bs + 2048 + w * 512;

    f32x4 acc[4][4] = {};
    for (int k0 = 0; k0 < DMODEL; k0 += 32) {
        __syncthreads();
        gl16(gA0 + k0, lA0);
        gl16(gA1 + k0, lA1);
        gl16(gB0 + k0, lB0);
        gl16(gB1 + k0, lB1);
        __syncthreads();
        bf16x8 af[4], bf[4];
#pragma unroll
        for (int mt = 0; mt < 4; ++mt)
            af[mt] = *(const bf16x8*)(&As[(wm * 64 + mt * 16 + fr) * 32 + fq * 8]);
#pragma unroll
        for (int nt = 0; nt < 4; ++nt)
            bf[nt] = *(const bf16x8*)(&Bs[(wn * 64 + nt * 16 + fr) * 32 + fq * 8]);
#pragma unroll
        for (int mt = 0; mt < 4; ++mt)
#pragma unroll
            for (int nt = 0; nt < 4; ++nt)
                acc[mt][nt] = __builtin_amdgcn_mfma_f32_16x16x32_bf16(af[mt], bf[nt], acc[mt][nt], 0, 0, 0);
    }
#pragma unroll
    for (int mt = 0; mt < 4; ++mt) {
#pragma unroll
        for (int nt = 0; nt < 4; ++nt) {
            int col = n0 + wn * 64 + nt * 16 + fr;
            if (col < DINPROJ) {
#pragma unroll
                for (int r = 0; r < 4; ++r) {
                    int row = m0 + wm * 64 + mt * 16 + fq * 4 + r;
                    C[(size_t)row * DINPROJ + col] = acc[mt][nt][r];
                }
            }
        }
    }
}

// ---------------- K2: causal depthwise conv + silu, and dt ------------------
__global__ __launch_bounds__(256) void k_conv_dt(const float* __restrict__ zx,
                                                 const float* __restrict__ conv_w,
                                                 const float* __restrict__ conv_b,
                                                 const float* __restrict__ dt_bias,
                                                 float* __restrict__ xbc,
                                                 float* __restrict__ dtb) {
    int row = blockIdx.y;                 // b*512 + l
    int c   = blockIdx.x * 256 + threadIdx.x;
    int b = row >> 9, l = row & 511;
    if (c < CONVDIM) {
        float acc = conv_b[c];
#pragma unroll
        for (int j = 0; j < 4; ++j) {
            int ls = l - 3 + j;
            float v = (ls >= 0) ? zx[((size_t)(b * SEQLEN + ls)) * DINPROJ + DINNER + c] : 0.f;
            acc += v * conv_w[c * 4 + j];
        }
        float s = acc / (1.f + expf(-acc));
        xbc[(size_t)row * CONVDIM + c] = s;
    } else if (c < CONVDIM + NHEADS) {
        int h = c - CONVDIM;
        float raw = zx[(size_t)row * DINPROJ + (DINNER + CONVDIM) + h] + dt_bias[h];
        float dt = (raw > 20.f) ? raw : log1pf(expf(raw));
        dtb[row * NHEADS + h] = dt;
    }
}

// ---------------- K3a: chunked SSD, intra-chunk (Y_intra + chunk state) ------
__global__ __launch_bounds__(256) void k_chunk(const float* __restrict__ xbc,
                                               const float* __restrict__ dtb,
                                               const float* __restrict__ A_log,
                                               const float* __restrict__ Dvec,
                                               float* __restrict__ yb,
                                               float* __restrict__ Sc_g,
                                               float* __restrict__ lam_g,
                                               float* __restrict__ esc_g) {
    const int gid = blockIdx.x;           // 0..511
    const int c = gid & 7;
    const int h = (gid >> 3) & 31;
    const int b = gid >> 8;
    const int row0 = b * SEQLEN + c * QC;

    __shared__ float cumS[QC], wS[QC], dtS[QC];
    __shared__ unsigned short Xt[QC][72];        // [p][s]
    __shared__ unsigned short Bs[QC][136];       // [s][n]
    __shared__ unsigned short BtW[DSTATE][72];   // [n][s], weighted by w[s]
    __shared__ unsigned short Cs[QC][136];       // [t][n]
    __shared__ unsigned short Gs[QC][72];        // [t][s], masked+decayed

    const int tid = threadIdx.x;
    if (tid < 64) {
        float dtv = dtb[(size_t)(row0 + tid) * NHEADS + h];
        float nA = -expf(A_log[h]);
        float x = dtv * nA;
#pragma unroll
        for (int off = 1; off < 64; off <<= 1) {
            float v = __shfl_up(x, off, 64);
            if (tid >= off) x += v;
        }
        float cumTot = __shfl(x, 63, 64);
        cumS[tid] = x;
        dtS[tid] = dtv;
        wS[tid] = expf(cumTot - x) * dtv;
        esc_g[(size_t)gid * QC + tid] = expf(x);
        if (tid == 0) lam_g[gid] = expf(cumTot);
    }
    __syncthreads();

    {
        int row = tid >> 2;       // s / t index 0..63
        int g = tid & 3;
        const float* rp = xbc + (size_t)(row0 + row) * CONVDIM;
        float wrow = wS[row];
#pragma unroll
        for (int i = 0; i < 4; ++i) {
            float4 v = *(const float4*)(rp + h * HEADDIM + g * 16 + i * 4);
            int p = g * 16 + i * 4;
            Xt[p + 0][row] = f2bf(v.x);
            Xt[p + 1][row] = f2bf(v.y);
            Xt[p + 2][row] = f2bf(v.z);
            Xt[p + 3][row] = f2bf(v.w);
        }
#pragma unroll
        for (int i = 0; i < 8; ++i) {
            int n = g * 32 + i * 4;
            float4 v = *(const float4*)(rp + DINNER + n);
            ushort4 u;
            u.x = f2bf(v.x); u.y = f2bf(v.y); u.z = f2bf(v.z); u.w = f2bf(v.w);
            *(ushort4*)(&Bs[row][n]) = u;
            BtW[n + 0][row] = f2bf(v.x * wrow);
            BtW[n + 1][row] = f2bf(v.y * wrow);
            BtW[n + 2][row] = f2bf(v.z * wrow);
            BtW[n + 3][row] = f2bf(v.w * wrow);
        }
#pragma unroll
        for (int i = 0; i < 8; ++i) {
            int n = g * 32 + i * 4;
            float4 v = *(const float4*)(rp + DINNER + DSTATE + n);
            ushort4 u;
            u.x = f2bf(v.x); u.y = f2bf(v.y); u.z = f2bf(v.z); u.w = f2bf(v.w);
            *(ushort4*)(&Cs[row][n]) = u;
        }
    }
    __syncthreads();

    const int w = tid >> 6, lane = tid & 63;
    const int fr = lane & 15, fq = lane >> 4, fk = (lane >> 4) * 8;

    f32x4 accG[4] = {};
#pragma unroll
    for (int kk = 0; kk < 4; ++kk) {
        bf16x8 a = *(const bf16x8*)(&Cs[w * 16 + fr][kk * 32 + fk]);
#pragma unroll
        for (int nt = 0; nt < 4; ++nt) {
            bf16x8 bb = *(const bf16x8*)(&Bs[nt * 16 + fr][kk * 32 + fk]);
            accG[nt] = __builtin_amdgcn_mfma_f32_16x16x32_bf16(a, bb, accG[nt], 0, 0, 0);
        }
    }
#pragma unroll
    for (int nt = 0; nt < 4; ++nt) {
        int s = nt * 16 + fr;
        float cs = cumS[s], dts = dtS[s];
#pragma unroll
        for (int r = 0; r < 4; ++r) {
            int t = w * 16 + fq * 4 + r;
            float val = (s <= t) ? accG[nt][r] * expf(cumS[t] - cs) * dts : 0.f;
            Gs[t][s] = f2bf(val);
        }
    }
    __syncthreads();

    f32x4 accY[4] = {};
#pragma unroll
    for (int kk = 0; kk < 2; ++kk) {
        bf16x8 a = *(const bf16x8*)(&Gs[w * 16 + fr][kk * 32 + fk]);
#pragma unroll
        for (int pt = 0; pt < 4; ++pt) {
            bf16x8 bb = *(const bf16x8*)(&Xt[pt * 16 + fr][kk * 32 + fk]);
            accY[pt] = __builtin_amdgcn_mfma_f32_16x16x32_bf16(a, bb, accY[pt], 0, 0, 0);
        }
    }
    f32x4 accS[8] = {};
#pragma unroll
    for (int kk = 0; kk < 2; ++kk) {
        bf16x8 a = *(const bf16x8*)(&Xt[w * 16 + fr][kk * 32 + fk]);
#pragma unroll
        for (int nt = 0; nt < 8; ++nt) {
            bf16x8 bb = *(const bf16x8*)(&BtW[nt * 16 + fr][kk * 32 + fk]);
            accS[nt] = __builtin_amdgcn_mfma_f32_16x16x32_bf16(a, bb, accS[nt], 0, 0, 0);
        }
    }
    float Dh = Dvec[h];
#pragma unroll
    for (int pt = 0; pt < 4; ++pt) {
        int p = pt * 16 + fr;
#pragma unroll
        for (int r = 0; r < 4; ++r) {
            int t = w * 16 + fq * 4 + r;
            float xv = xbc[(size_t)(row0 + t) * CONVDIM + h * HEADDIM + p];
            yb[(size_t)(row0 + t) * DINNER + h * HEADDIM + p] = accY[pt][r] + Dh * xv;
        }
    }
    float* scp = Sc_g + (size_t)gid * (HEADDIM * DSTATE);
#pragma unroll
    for (int nt = 0; nt < 8; ++nt) {
        int n = nt * 16 + fr;
#pragma unroll
        for (int r = 0; r < 4; ++r) {
            int p = w * 16 + fq * 4 + r;
            scp[p * DSTATE + n] = accS[nt][r];
        }
    }
}

// ---------------- K3b: inter-chunk state chain (sequential over 8 chunks) ----
__global__ __launch_bounds__(256) void k_chain(const float* __restrict__ Sc_g,
                                               const float* __restrict__ lam_g,
                                               unsigned short* __restrict__ Sin_bf) {
    int bh = blockIdx.x;           // 0..63
    int tid = threadIdx.x;
    float s[32];
#pragma unroll
    for (int i = 0; i < 32; ++i) s[i] = 0.f;
    for (int c = 0; c < NCH; ++c) {
        size_t base = (size_t)(bh * NCH + c) * (HEADDIM * DSTATE) + tid * 32;
#pragma unroll
        for (int j = 0; j < 32; j += 4) {
            ushort4 u;
            u.x = f2bf(s[j + 0]); u.y = f2bf(s[j + 1]);
            u.z = f2bf(s[j + 2]); u.w = f2bf(s[j + 3]);
            *(ushort4*)(Sin_bf + base + j) = u;
        }
        float lam = lam_g[bh * NCH + c];
#pragma unroll
        for (int j = 0; j < 32; j += 4) {
            float4 v = *(const float4*)(Sc_g + base + j);
            s[j + 0] = s[j + 0] * lam + v.x;
            s[j + 1] = s[j + 1] * lam + v.y;
            s[j + 2] = s[j + 2] * lam + v.z;
            s[j + 3] = s[j + 3] * lam + v.w;
        }
    }
}

// ---------------- K3c: cross-chunk term: Y += exp(cum[t]) * C_t · S_in -------
__global__ __launch_bounds__(256) void k_cross(const float* __restrict__ xbc,
                                               const float* __restrict__ esc_g,
                                               const unsigned short* __restrict__ Sin_bf,
                                               float* __restrict__ yb) {
    const int gid = blockIdx.x;
    const int c = gid & 7;
    const int h = (gid >> 3) & 31;
    const int b = gid >> 8;
    const int row0 = b * SEQLEN + c * QC;
    __shared__ unsigned short Ct[QC][136];   // [t][n], scaled by esc[t]
    __shared__ unsigned short Ss[QC][136];   // [p][n]
    const int tid = threadIdx.x;
    {
        int row = tid >> 2, g = tid & 3;
        const float* rp = xbc + (size_t)(row0 + row) * CONVDIM + DINNER + DSTATE;
        float esc = esc_g[(size_t)gid * QC + row];
#pragma unroll
        for (int i = 0; i < 8; ++i) {
            int n = g * 32 + i * 4;
            float4 v = *(const float4*)(rp + n);
            ushort4 u;
            u.x = f2bf(v.x * esc); u.y = f2bf(v.y * esc);
            u.z = f2bf(v.z * esc); u.w = f2bf(v.w * esc);
            *(ushort4*)(&Ct[row][n]) = u;
        }
        const uint4* sp = (const uint4*)(Sin_bf + (size_t)gid * (HEADDIM * DSTATE));
#pragma unroll
        for (int i = 0; i < 4; ++i) {
            uint4 v = sp[row * 16 + g * 4 + i];
            *(uint4*)(&Ss[row][g * 32 + i * 8]) = v;
        }
    }
    __syncthreads();
    const int w = tid >> 6, lane = tid & 63;
    const int fr = lane & 15, fq = lane >> 4, fk = (lane >> 4) * 8;
    f32x4 acc[4] = {};
#pragma unroll
    for (int kk = 0; kk < 4; ++kk) {
        bf16x8 a = *(const bf16x8*)(&Ct[w * 16 + fr][kk * 32 + fk]);
#pragma unroll
        for (int pt = 0; pt < 4; ++pt) {
            bf16x8 bb = *(const bf16x8*)(&Ss[pt * 16 + fr][kk * 32 + fk]);
            acc[pt] = __builtin_amdgcn_mfma_f32_16x16x32_bf16(a, bb, acc[pt], 0, 0, 0);
        }
    }
#pragma unroll
    for (int pt = 0; pt < 4; ++pt) {
        int p = pt * 16 + fr;
#pragma unroll
        for (int r = 0; r < 4; ++r) {
            int t = w * 16 + fq * 4 + r;
            size_t yi = (size_t)(row0 + t) * DINNER + h * HEADDIM + p;
            yb[yi] += acc[pt][r];
        }
    }
}

// ---------------- K4a: gated RMSNorm -> bf16 G -------------------------------
__global__ __launch_bounds__(256) void k_gate_norm(const float* __restrict__ zx,
                                                   const float* __restrict__ nw,
                                                   const float* __restrict__ y,
                                                   unsigned short* __restrict__ Gbf) {
    int row = blockIdx.x;
    int tid = threadIdx.x;
    const float* zrow = zx + (size_t)row * DINPROJ;   // z = cols [0,2048)
    const float* yr = y + (size_t)row * DINNER;
    float g[8];
    float ss = 0.f;
#pragma unroll
    for (int i = 0; i < 2; ++i) {
        int c = tid * 4 + i * 1024;
        float4 yv = *(const float4*)(yr + c);
        float4 zv = *(const float4*)(zrow + c);
        float zs[4] = {zv.x, zv.y, zv.z, zv.w};
        float ys[4] = {yv.x, yv.y, yv.z, yv.w};
#pragma unroll
        for (int k = 0; k < 4; ++k) {
            float sil = zs[k] / (1.f + expf(-zs[k]));
            float gg = ys[k] * sil;
            g[i * 4 + k] = gg;
            ss += gg * gg;
        }
    }
#pragma unroll
    for (int off = 32; off >= 1; off >>= 1) ss += __shfl_xor(ss, off, 64);
    __shared__ float wsum[4];
    if ((tid & 63) == 0) wsum[tid >> 6] = ss;
    __syncthreads();
    float tot = wsum[0] + wsum[1] + wsum[2] + wsum[3];
    float scale = rsqrtf(tot / (float)DINNER + 1e-5f);
#pragma unroll
    for (int i = 0; i < 2; ++i) {
        int c = tid * 4 + i * 1024;
        float4 nv = *(const float4*)(nw + c);
        ushort4 o;
        o.x = f2bf(g[i * 4 + 0] * scale * nv.x);
        o.y = f2bf(g[i * 4 + 1] * scale * nv.y);
        o.z = f2bf(g[i * 4 + 2] * scale * nv.z);
        o.w = f2bf(g[i * 4 + 3] * scale * nv.w);
        *(ushort4*)(Gbf + (size_t)row * DINNER + c) = o;
    }
}

// ---------------- K4b: classifier GEMM (split-K, MFMA, atomicAdd) ------------
__global__ __launch_bounds__(256) void k_cls_mfma(const unsigned short* __restrict__ G,
                                                  const unsigned short* __restrict__ Wt,
                                                  float* __restrict__ out) {
    __shared__ unsigned short Gs[64][72];
    __shared__ unsigned short Ws[48][72];
    const int m0  = blockIdx.x * 64;
    const int k00 = blockIdx.y * 256;
    const int tid = threadIdx.x;
    const int w = tid >> 6, lane = tid & 63;
    const int fr = lane & 15, fq = lane >> 4, fk = fq * 8;
    f32x4 acc[3] = {};
    for (int ks = 0; ks < 4; ++ks) {
        int k0 = k00 + ks * 64;
        __syncthreads();
        {
            int row = tid >> 2, seg = (tid & 3) * 16;
            const unsigned short* gp = G + (size_t)(m0 + row) * DINNER + k0 + seg;
            *(uint4*)(&Gs[row][seg])     = *(const uint4*)(gp);
            *(uint4*)(&Gs[row][seg + 8]) = *(const uint4*)(gp + 8);
        }
        if (tid < 192) {
            int row = tid >> 2, seg = (tid & 3) * 16;
            const unsigned short* wp = Wt + (size_t)row * DINNER + k0 + seg;
            *(uint4*)(&Ws[row][seg])     = *(const uint4*)(wp);
            *(uint4*)(&Ws[row][seg + 8]) = *(const uint4*)(wp + 8);
        }
        __syncthreads();
#pragma unroll
        for (int kk = 0; kk < 2; ++kk) {
            bf16x8 a = *(const bf16x8*)(&Gs[w * 16 + fr][kk * 32 + fk]);
#pragma unroll
            for (int nt = 0; nt < 3; ++nt) {
                bf16x8 bb = *(const bf16x8*)(&Ws[nt * 16 + fr][kk * 32 + fk]);
                acc[nt] = __builtin_amdgcn_mfma_f32_16x16x32_bf16(a, bb, acc[nt], 0, 0, 0);
            }
        }
    }
#pragma unroll
    for (int nt = 0; nt < 3; ++nt) {
        int col = nt * 16 + fr;
#pragma unroll
        for (int r = 0; r < 4; ++r) {
            int row = m0 + w * 16 + fq * 4 + r;
            atomicAdd(&out[(size_t)row * NCLS + col], acc[nt][r]);
        }
    }
}

// ---------------- launch -----------------------------------------------------
extern "C" void kernel_launch(void* const* d_in, const int* in_sizes, int n_in,
                              void* d_out, int out_size, void* d_ws, size_t ws_size,
                              hipStream_t stream) {
    const float* inputs  = (const float*)d_in[0];
    const float* W_in    = (const float*)d_in[1];
    const float* conv_w  = (const float*)d_in[2];
    const float* conv_b  = (const float*)d_in[3];
    const float* dt_bias = (const float*)d_in[4];
    const float* A_log   = (const float*)d_in[5];
    const float* Dvec    = (const float*)d_in[6];
    const float* norm_w  = (const float*)d_in[7];
    // d_in[8] = W_out (unused by reference output)
    const float* W_cls   = (const float*)d_in[9];
    const float* b_cls   = (const float*)d_in[10];
    float* out = (float*)d_out;

    // workspace layout
    float* ws   = (float*)d_ws;
    float* zx   = ws;                            // BL*4384
    float* xbc  = zx   + (size_t)BL * DINPROJ;   // BL*2304
    float* dtb  = xbc  + (size_t)BL * CONVDIM;   // BL*32
    float* yb   = dtb  + (size_t)BL * NHEADS;    // BL*2048
    float* Sc_g = yb   + (size_t)BL * DINNER;    // 512*8192 (dead after k_chain; Gbf aliases it)
    float* lam_g= Sc_g + (size_t)BATCH * NHEADS * NCH * HEADDIM * DSTATE;  // 512
    float* esc_g= lam_g+ (size_t)BATCH * NHEADS * NCH;                     // 512*64
    unsigned short* Sin_bf = (unsigned short*)(esc_g + (size_t)BATCH * NHEADS * NCH * QC);
    unsigned short* abf    = Sin_bf + (size_t)BATCH * NHEADS * NCH * HEADDIM * DSTATE;
    unsigned short* wtbf   = abf + (size_t)BL * DMODEL;                    // 4480*1024 (padded)
    unsigned short* wclsbf = wtbf + (size_t)NPROJPAD * DMODEL;             // 48*2048
    unsigned short* Gbf    = (unsigned short*)Sc_g;  // alias: Sc_g is dead post-k_chain

    k_cvt_a<<<dim3(BL * DMODEL / (256 * 4)), dim3(256), 0, stream>>>(inputs, abf);
    k_transpose_w<<<dim3(DINPROJ / 32, DMODEL / 32), dim3(256), 0, stream>>>(W_in, wtbf);
    k_prep_cls<<<dim3(240), dim3(256), 0, stream>>>(W_cls, b_cls, wclsbf, out);
    k_gemm_in<<<dim3(NPROJPAD / 128, BL / 128), dim3(256), 0, stream>>>(abf, wtbf, zx);
    k_conv_dt<<<dim3(10, BL), dim3(256), 0, stream>>>(zx, conv_w, conv_b, dt_bias, xbc, dtb);
    k_chunk<<<dim3(BATCH * NHEADS * NCH), dim3(256), 0, stream>>>(xbc, dtb, A_log, Dvec,
                                                                  yb, Sc_g, lam_g, esc_g);
    k_chain<<<dim3(BATCH * NHEADS), dim3(256), 0, stream>>>(Sc_g, lam_g, Sin_bf);
    k_cross<<<dim3(BATCH * NHEADS * NCH), dim3(256), 0, stream>>>(xbc, esc_g, Sin_bf, yb);
    k_gate_norm<<<dim3(BL), dim3(256), 0, stream>>>(zx, norm_w, yb, Gbf);
    k_cls_mfma<<<dim3(BL / 64, 8), dim3(256), 0, stream>>>(Gbf, wclsbf, out);
}

// Round 5
// 171.369 us; speedup vs baseline: 3.3829x; 1.0745x over previous
//
#include <hip/hip_runtime.h>
#include <hip/hip_bf16.h>
#include <cstdint>

// Problem constants
#define BATCH 2
#define SEQLEN 512
#define BL (BATCH*SEQLEN)       // 1024 rows
#define DMODEL 1024
#define DINNER 2048
#define NHEADS 32
#define HEADDIM 64
#define DSTATE 128
#define CONVDIM 2304            // DINNER + 2*DSTATE
#define DINPROJ 4384            // 2*DINNER + 2*DSTATE + NHEADS
#define NPROJPAD 4480           // DINPROJ padded to 128 multiple (DMA-safe N tail)
#define NCLS 48
#define QC 64                   // scan chunk length
#define NCH 8                   // chunks per sequence (SEQLEN/QC)

typedef short bf16x8 __attribute__((ext_vector_type(8)));
typedef float f32x4  __attribute__((ext_vector_type(4)));
typedef unsigned int u32;
typedef const __attribute__((address_space(1))) u32 gu32;
typedef __attribute__((address_space(3))) u32 lu32;

static __device__ __forceinline__ void gl16(const void* g, void* l) {
    // async global->LDS DMA, 16B/lane; LDS dest = wave-uniform base + lane*16
    __builtin_amdgcn_global_load_lds((gu32*)g, (lu32*)l, 16, 0, 0);
}

static __device__ __forceinline__ unsigned short f2bf(float f) {
    unsigned u = __float_as_uint(f);
    unsigned r = (u + 0x7FFFu + ((u >> 16) & 1u)) >> 16;
    return (unsigned short)r;
}
static __device__ __forceinline__ float bf2f(unsigned short u) {
    return __uint_as_float(((unsigned)u) << 16);
}

// ---------------- K0a: inputs fp32 -> bf16 (row-major 1024x1024) -------------
__global__ __launch_bounds__(256) void k_cvt_a(const float* __restrict__ in,
                                               unsigned short* __restrict__ out) {
    int i = (blockIdx.x * 256 + threadIdx.x) * 4;
    float4 v = *(const float4*)(in + i);
    ushort4 o;
    o.x = f2bf(v.x); o.y = f2bf(v.y); o.z = f2bf(v.z); o.w = f2bf(v.w);
    *(ushort4*)(out + i) = o;
}

// ---------------- K0b: W_in (1024x4384) -> Wt bf16 (4384x1024) ---------------
__global__ __launch_bounds__(256) void k_transpose_w(const float* __restrict__ W,
                                                     unsigned short* __restrict__ Wt) {
    __shared__ float tile[32][33];
    int n0 = blockIdx.x * 32;
    int k0 = blockIdx.y * 32;
    int tx = threadIdx.x & 31;
    int ty = threadIdx.x >> 5;
#pragma unroll
    for (int i = 0; i < 4; ++i) {
        int k = k0 + ty + i * 8;
        tile[ty + i * 8][tx] = W[(size_t)k * DINPROJ + n0 + tx];
    }
    __syncthreads();
#pragma unroll
    for (int i = 0; i < 4; ++i) {
        int n = n0 + ty + i * 8;
        Wt[(size_t)n * DMODEL + k0 + tx] = f2bf(tile[tx][ty + i * 8]);
    }
}

// ---------------- K0c: classifier prep: out=bias broadcast + W_cls^T bf16 ----
__global__ __launch_bounds__(256) void k_prep_cls(const float* __restrict__ W,
                                                  const float* __restrict__ bcls,
                                                  unsigned short* __restrict__ Wt,
                                                  float* __restrict__ out) {
    int bid = blockIdx.x;
    if (bid < 192) {                       // 192*256 = 1024*48
        int i = bid * 256 + threadIdx.x;
        out[i] = bcls[i % NCLS];
    } else {
        int n = bid - 192;                 // 0..47
        for (int k = threadIdx.x; k < DINNER; k += 256)
            Wt[(size_t)n * DINNER + k] = f2bf(W[(size_t)k * NCLS + n]);
    }
}

// ---------------- K1: zxbcdt = A(1024x1024) @ W(1024x4384) -> bf16 -----------
// 128x128 tile, BK=64 as TWO BK=32 half-tiles (keeps m97 conflict-free layout),
// global_load_lds width=16, 4 waves in 2x2, 32 MFMA/wave per K-iteration.
__global__ __launch_bounds__(256) void k_gemm_in(const unsigned short* __restrict__ A,
                                                 const unsigned short* __restrict__ Bt,
                                                 unsigned short* __restrict__ C) {
    __shared__ unsigned short As[2 * 4096];   // [half][128][32] unpadded (DMA layout)
    __shared__ unsigned short Bs[2 * 4096];
    const int tid  = threadIdx.x;
    const int m0   = blockIdx.y * 128;
    const int n0   = blockIdx.x * 128;
    const int w    = tid >> 6;            // wave 0..3
    const int lane = tid & 63;
    const int wm   = w >> 1, wn = w & 1;
    const int fr   = lane & 15, fq = lane >> 4;
    // staging: wave w handles rows [w*16,+16) (chunk 0) and [64+w*16,+16) (chunk 1)
    const int srow = w * 16 + (lane >> 2);
    const int skg  = (lane & 3) * 8;      // k-offset in ushorts within a 32-half
    const unsigned short* gA0 = A  + (size_t)(m0 + srow) * DMODEL + skg;
    const unsigned short* gA1 = gA0 + (size_t)64 * DMODEL;
    const unsigned short* gB0 = Bt + (size_t)(n0 + srow) * DMODEL + skg;
    const unsigned short* gB1 = gB0 + (size_t)64 * DMODEL;

    f32x4 acc[4][4] = {};
    for (int k0 = 0; k0 < DMODEL; k0 += 64) {
        __syncthreads();
#pragma unroll
        for (int hh = 0; hh < 2; ++hh) {
            int kg = k0 + hh * 32;
            gl16(gA0 + kg, As + hh * 4096 + w * 512);
            gl16(gA1 + kg, As + hh * 4096 + 2048 + w * 512);
            gl16(gB0 + kg, Bs + hh * 4096 + w * 512);
            gl16(gB1 + kg, Bs + hh * 4096 + 2048 + w * 512);
        }
        __syncthreads();
#pragma unroll
        for (int hh = 0; hh < 2; ++hh) {
            bf16x8 af[4], bf[4];
#pragma unroll
            for (int mt = 0; mt < 4; ++mt)
                af[mt] = *(const bf16x8*)(&As[hh * 4096 + (wm * 64 + mt * 16 + fr) * 32 + fq * 8]);
#pragma unroll
            for (int nt = 0; nt < 4; ++nt)
                bf[nt] = *(const bf16x8*)(&Bs[hh * 4096 + (wn * 64 + nt * 16 + fr) * 32 + fq * 8]);
#pragma unroll
            for (int mt = 0; mt < 4; ++mt)
#pragma unroll
                for (int nt = 0; nt < 4; ++nt)
                    acc[mt][nt] = __builtin_amdgcn_mfma_f32_16x16x32_bf16(af[mt], bf[nt], acc[mt][nt], 0, 0, 0);
        }
    }
#pragma unroll
    for (int mt = 0; mt < 4; ++mt) {
#pragma unroll
        for (int nt = 0; nt < 4; ++nt) {
            int col = n0 + wn * 64 + nt * 16 + fr;
            if (col < DINPROJ) {
#pragma unroll
                for (int r = 0; r < 4; ++r) {
                    int row = m0 + wm * 64 + mt * 16 + fq * 4 + r;
                    C[(size_t)row * DINPROJ + col] = f2bf(acc[mt][nt][r]);
                }
            }
        }
    }
}

// ---------------- K2: causal depthwise conv + silu, and dt (bf16 zx) ---------
__global__ __launch_bounds__(256) void k_conv_dt(const unsigned short* __restrict__ zx,
                                                 const float* __restrict__ conv_w,
                                                 const float* __restrict__ conv_b,
                                                 const float* __restrict__ dt_bias,
                                                 float* __restrict__ xbc,
                                                 float* __restrict__ dtb) {
    int row = blockIdx.y;                 // b*512 + l
    int c   = blockIdx.x * 256 + threadIdx.x;
    int b = row >> 9, l = row & 511;
    if (c < CONVDIM) {
        float acc = conv_b[c];
#pragma unroll
        for (int j = 0; j < 4; ++j) {
            int ls = l - 3 + j;
            float v = (ls >= 0) ? bf2f(zx[((size_t)(b * SEQLEN + ls)) * DINPROJ + DINNER + c]) : 0.f;
            acc += v * conv_w[c * 4 + j];
        }
        float s = acc / (1.f + expf(-acc));
        xbc[(size_t)row * CONVDIM + c] = s;
    } else if (c < CONVDIM + NHEADS) {
        int h = c - CONVDIM;
        float raw = bf2f(zx[(size_t)row * DINPROJ + (DINNER + CONVDIM) + h]) + dt_bias[h];
        float dt = (raw > 20.f) ? raw : log1pf(expf(raw));
        dtb[row * NHEADS + h] = dt;
    }
}

// ---------------- K3a: chunked SSD, intra-chunk (Y_intra + chunk state) ------
__global__ __launch_bounds__(256) void k_chunk(const float* __restrict__ xbc,
                                               const float* __restrict__ dtb,
                                               const float* __restrict__ A_log,
                                               const float* __restrict__ Dvec,
                                               float* __restrict__ yb,
                                               float* __restrict__ Sc_g,
                                               float* __restrict__ lam_g,
                                               float* __restrict__ esc_g) {
    const int gid = blockIdx.x;           // 0..511
    const int c = gid & 7;
    const int h = (gid >> 3) & 31;
    const int b = gid >> 8;
    const int row0 = b * SEQLEN + c * QC;

    __shared__ float cumS[QC], wS[QC], dtS[QC];
    __shared__ unsigned short Xt[QC][72];        // [p][s]
    __shared__ unsigned short Bs[QC][136];       // [s][n]
    __shared__ unsigned short BtW[DSTATE][72];   // [n][s], weighted by w[s]
    __shared__ unsigned short Cs[QC][136];       // [t][n]
    __shared__ unsigned short Gs[QC][72];        // [t][s], masked+decayed

    const int tid = threadIdx.x;
    if (tid < 64) {
        float dtv = dtb[(size_t)(row0 + tid) * NHEADS + h];
        float nA = -expf(A_log[h]);
        float x = dtv * nA;
#pragma unroll
        for (int off = 1; off < 64; off <<= 1) {
            float v = __shfl_up(x, off, 64);
            if (tid >= off) x += v;
        }
        float cumTot = __shfl(x, 63, 64);
        cumS[tid] = x;
        dtS[tid] = dtv;
        wS[tid] = expf(cumTot - x) * dtv;
        esc_g[(size_t)gid * QC + tid] = expf(x);
        if (tid == 0) lam_g[gid] = expf(cumTot);
    }
    __syncthreads();

    {
        int row = tid >> 2;       // s / t index 0..63
        int g = tid & 3;
        const float* rp = xbc + (size_t)(row0 + row) * CONVDIM;
        float wrow = wS[row];
#pragma unroll
        for (int i = 0; i < 4; ++i) {
            float4 v = *(const float4*)(rp + h * HEADDIM + g * 16 + i * 4);
            int p = g * 16 + i * 4;
            Xt[p + 0][row] = f2bf(v.x);
            Xt[p + 1][row] = f2bf(v.y);
            Xt[p + 2][row] = f2bf(v.z);
            Xt[p + 3][row] = f2bf(v.w);
        }
#pragma unroll
        for (int i = 0; i < 8; ++i) {
            int n = g * 32 + i * 4;
            float4 v = *(const float4*)(rp + DINNER + n);
            ushort4 u;
            u.x = f2bf(v.x); u.y = f2bf(v.y); u.z = f2bf(v.z); u.w = f2bf(v.w);
            *(ushort4*)(&Bs[row][n]) = u;
            BtW[n + 0][row] = f2bf(v.x * wrow);
            BtW[n + 1][row] = f2bf(v.y * wrow);
            BtW[n + 2][row] = f2bf(v.z * wrow);
            BtW[n + 3][row] = f2bf(v.w * wrow);
        }
#pragma unroll
        for (int i = 0; i < 8; ++i) {
            int n = g * 32 + i * 4;
            float4 v = *(const float4*)(rp + DINNER + DSTATE + n);
            ushort4 u;
            u.x = f2bf(v.x); u.y = f2bf(v.y); u.z = f2bf(v.z); u.w = f2bf(v.w);
            *(ushort4*)(&Cs[row][n]) = u;
        }
    }
    __syncthreads();

    const int w = tid >> 6, lane = tid & 63;
    const int fr = lane & 15, fq = lane >> 4, fk = (lane >> 4) * 8;

    f32x4 accG[4] = {};
#pragma unroll
    for (int kk = 0; kk < 4; ++kk) {
        bf16x8 a = *(const bf16x8*)(&Cs[w * 16 + fr][kk * 32 + fk]);
#pragma unroll
        for (int nt = 0; nt < 4; ++nt) {
            bf16x8 bb = *(const bf16x8*)(&Bs[nt * 16 + fr][kk * 32 + fk]);
            accG[nt] = __builtin_amdgcn_mfma_f32_16x16x32_bf16(a, bb, accG[nt], 0, 0, 0);
        }
    }
#pragma unroll
    for (int nt = 0; nt < 4; ++nt) {
        int s = nt * 16 + fr;
        float cs = cumS[s], dts = dtS[s];
#pragma unroll
        for (int r = 0; r < 4; ++r) {
            int t = w * 16 + fq * 4 + r;
            float val = (s <= t) ? accG[nt][r] * expf(cumS[t] - cs) * dts : 0.f;
            Gs[t][s] = f2bf(val);
        }
    }
    __syncthreads();

    f32x4 accY[4] = {};
#pragma unroll
    for (int kk = 0; kk < 2; ++kk) {
        bf16x8 a = *(const bf16x8*)(&Gs[w * 16 + fr][kk * 32 + fk]);
#pragma unroll
        for (int pt = 0; pt < 4; ++pt) {
            bf16x8 bb = *(const bf16x8*)(&Xt[pt * 16 + fr][kk * 32 + fk]);
            accY[pt] = __builtin_amdgcn_mfma_f32_16x16x32_bf16(a, bb, accY[pt], 0, 0, 0);
        }
    }
    f32x4 accS[8] = {};
#pragma unroll
    for (int kk = 0; kk < 2; ++kk) {
        bf16x8 a = *(const bf16x8*)(&Xt[w * 16 + fr][kk * 32 + fk]);
#pragma unroll
        for (int nt = 0; nt < 8; ++nt) {
            bf16x8 bb = *(const bf16x8*)(&BtW[nt * 16 + fr][kk * 32 + fk]);
            accS[nt] = __builtin_amdgcn_mfma_f32_16x16x32_bf16(a, bb, accS[nt], 0, 0, 0);
        }
    }
    float Dh = Dvec[h];
#pragma unroll
    for (int pt = 0; pt < 4; ++pt) {
        int p = pt * 16 + fr;
#pragma unroll
        for (int r = 0; r < 4; ++r) {
            int t = w * 16 + fq * 4 + r;
            float xv = xbc[(size_t)(row0 + t) * CONVDIM + h * HEADDIM + p];
            yb[(size_t)(row0 + t) * DINNER + h * HEADDIM + p] = accY[pt][r] + Dh * xv;
        }
    }
    float* scp = Sc_g + (size_t)gid * (HEADDIM * DSTATE);
#pragma unroll
    for (int nt = 0; nt < 8; ++nt) {
        int n = nt * 16 + fr;
#pragma unroll
        for (int r = 0; r < 4; ++r) {
            int p = w * 16 + fq * 4 + r;
            scp[p * DSTATE + n] = accS[nt][r];
        }
    }
}

// ---------------- K3b: inter-chunk state chain (256 WGs, serial over 8) ------
__global__ __launch_bounds__(256) void k_chain(const float* __restrict__ Sc_g,
                                               const float* __restrict__ lam_g,
                                               unsigned short* __restrict__ Sin_bf) {
    int bh = blockIdx.x >> 2;      // 0..63
    int sl = blockIdx.x & 3;       // slice 0..3 of the 8192-elem state
    int tid = threadIdx.x;
    float s[8];
#pragma unroll
    for (int i = 0; i < 8; ++i) s[i] = 0.f;
    for (int c = 0; c < NCH; ++c) {
        size_t base = (size_t)(bh * NCH + c) * (HEADDIM * DSTATE) + sl * 2048 + tid * 8;
#pragma unroll
        for (int j = 0; j < 8; j += 4) {
            ushort4 u;
            u.x = f2bf(s[j + 0]); u.y = f2bf(s[j + 1]);
            u.z = f2bf(s[j + 2]); u.w = f2bf(s[j + 3]);
            *(ushort4*)(Sin_bf + base + j) = u;
        }
        float lam = lam_g[bh * NCH + c];
#pragma unroll
        for (int j = 0; j < 8; j += 4) {
            float4 v = *(const float4*)(Sc_g + base + j);
            s[j + 0] = s[j + 0] * lam + v.x;
            s[j + 1] = s[j + 1] * lam + v.y;
            s[j + 2] = s[j + 2] * lam + v.z;
            s[j + 3] = s[j + 3] * lam + v.w;
        }
    }
}

// ---------------- K3c: cross-chunk term: Y += exp(cum[t]) * C_t · S_in -------
__global__ __launch_bounds__(256) void k_cross(const float* __restrict__ xbc,
                                               const float* __restrict__ esc_g,
                                               const unsigned short* __restrict__ Sin_bf,
                                               float* __restrict__ yb) {
    const int gid = blockIdx.x;
    const int c = gid & 7;
    const int h = (gid >> 3) & 31;
    const int b = gid >> 8;
    const int row0 = b * SEQLEN + c * QC;
    __shared__ unsigned short Ct[QC][136];   // [t][n], scaled by esc[t]
    __shared__ unsigned short Ss[QC][136];   // [p][n]
    const int tid = threadIdx.x;
    {
        int row = tid >> 2, g = tid & 3;
        const float* rp = xbc + (size_t)(row0 + row) * CONVDIM + DINNER + DSTATE;
        float esc = esc_g[(size_t)gid * QC + row];
#pragma unroll
        for (int i = 0; i < 8; ++i) {
            int n = g * 32 + i * 4;
            float4 v = *(const float4*)(rp + n);
            ushort4 u;
            u.x = f2bf(v.x * esc); u.y = f2bf(v.y * esc);
            u.z = f2bf(v.z * esc); u.w = f2bf(v.w * esc);
            *(ushort4*)(&Ct[row][n]) = u;
        }
        const uint4* sp = (const uint4*)(Sin_bf + (size_t)gid * (HEADDIM * DSTATE));
#pragma unroll
        for (int i = 0; i < 4; ++i) {
            uint4 v = sp[row * 16 + g * 4 + i];
            *(uint4*)(&Ss[row][g * 32 + i * 8]) = v;
        }
    }
    __syncthreads();
    const int w = tid >> 6, lane = tid & 63;
    const int fr = lane & 15, fq = lane >> 4, fk = (lane >> 4) * 8;
    f32x4 acc[4] = {};
#pragma unroll
    for (int kk = 0; kk < 4; ++kk) {
        bf16x8 a = *(const bf16x8*)(&Ct[w * 16 + fr][kk * 32 + fk]);
#pragma unroll
        for (int pt = 0; pt < 4; ++pt) {
            bf16x8 bb = *(const bf16x8*)(&Ss[pt * 16 + fr][kk * 32 + fk]);
            acc[pt] = __builtin_amdgcn_mfma_f32_16x16x32_bf16(a, bb, acc[pt], 0, 0, 0);
        }
    }
#pragma unroll
    for (int pt = 0; pt < 4; ++pt) {
        int p = pt * 16 + fr;
#pragma unroll
        for (int r = 0; r < 4; ++r) {
            int t = w * 16 + fq * 4 + r;
            size_t yi = (size_t)(row0 + t) * DINNER + h * HEADDIM + p;
            yb[yi] += acc[pt][r];
        }
    }
}

// ---------------- K4a: gated RMSNorm -> bf16 G (z from bf16 zx) --------------
__global__ __launch_bounds__(256) void k_gate_norm(const unsigned short* __restrict__ zx,
                                                   const float* __restrict__ nw,
                                                   const float* __restrict__ y,
                                                   unsigned short* __restrict__ Gbf) {
    int row = blockIdx.x;
    int tid = threadIdx.x;
    const unsigned short* zrow = zx + (size_t)row * DINPROJ;   // z = cols [0,2048)
    const float* yr = y + (size_t)row * DINNER;
    float g[8];
    float ss = 0.f;
#pragma unroll
    for (int i = 0; i < 2; ++i) {
        int c = tid * 4 + i * 1024;
        float4 yv = *(const float4*)(yr + c);
        ushort4 zv = *(const ushort4*)(zrow + c);
        float zs[4] = {bf2f(zv.x), bf2f(zv.y), bf2f(zv.z), bf2f(zv.w)};
        float ys[4] = {yv.x, yv.y, yv.z, yv.w};
#pragma unroll
        for (int k = 0; k < 4; ++k) {
            float sil = zs[k] / (1.f + expf(-zs[k]));
            float gg = ys[k] * sil;
            g[i * 4 + k] = gg;
            ss += gg * gg;
        }
    }
#pragma unroll
    for (int off = 32; off >= 1; off >>= 1) ss += __shfl_xor(ss, off, 64);
    __shared__ float wsum[4];
    if ((tid & 63) == 0) wsum[tid >> 6] = ss;
    __syncthreads();
    float tot = wsum[0] + wsum[1] + wsum[2] + wsum[3];
    float scale = rsqrtf(tot / (float)DINNER + 1e-5f);
#pragma unroll
    for (int i = 0; i < 2; ++i) {
        int c = tid * 4 + i * 1024;
        float4 nv = *(const float4*)(nw + c);
        ushort4 o;
        o.x = f2bf(g[i * 4 + 0] * scale * nv.x);
        o.y = f2bf(g[i * 4 + 1] * scale * nv.y);
        o.z = f2bf(g[i * 4 + 2] * scale * nv.z);
        o.w = f2bf(g[i * 4 + 3] * scale * nv.w);
        *(ushort4*)(Gbf + (size_t)row * DINNER + c) = o;
    }
}

// ---------------- K4b: classifier GEMM (split-K, MFMA, atomicAdd) ------------
__global__ __launch_bounds__(256) void k_cls_mfma(const unsigned short* __restrict__ G,
                                                  const unsigned short* __restrict__ Wt,
                                                  float* __restrict__ out) {
    __shared__ unsigned short Gs[64][72];
    __shared__ unsigned short Ws[48][72];
    const int m0  = blockIdx.x * 64;
    const int k00 = blockIdx.y * 256;
    const int tid = threadIdx.x;
    const int w = tid >> 6, lane = tid & 63;
    const int fr = lane & 15, fq = lane >> 4, fk = fq * 8;
    f32x4 acc[3] = {};
    for (int ks = 0; ks < 4; ++ks) {
        int k0 = k00 + ks * 64;
        __syncthreads();
        {
            int row = tid >> 2, seg = (tid & 3) * 16;
            const unsigned short* gp = G + (size_t)(m0 + row) * DINNER + k0 + seg;
            *(uint4*)(&Gs[row][seg])     = *(const uint4*)(gp);
            *(uint4*)(&Gs[row][seg + 8]) = *(const uint4*)(gp + 8);
        }
        if (tid < 192) {
            int row = tid >> 2, seg = (tid & 3) * 16;
            const unsigned short* wp = Wt + (size_t)row * DINNER + k0 + seg;
            *(uint4*)(&Ws[row][seg])     = *(const uint4*)(wp);
            *(uint4*)(&Ws[row][seg + 8]) = *(const uint4*)(wp + 8);
        }
        __syncthreads();
#pragma unroll
        for (int kk = 0; kk < 2; ++kk) {
            bf16x8 a = *(const bf16x8*)(&Gs[w * 16 + fr][kk * 32 + fk]);
#pragma unroll
            for (int nt = 0; nt < 3; ++nt) {
                bf16x8 bb = *(const bf16x8*)(&Ws[nt * 16 + fr][kk * 32 + fk]);
                acc[nt] = __builtin_amdgcn_mfma_f32_16x16x32_bf16(a, bb, acc[nt], 0, 0, 0);
            }
        }
    }
#pragma unroll
    for (int nt = 0; nt < 3; ++nt) {
        int col = nt * 16 + fr;
#pragma unroll
        for (int r = 0; r < 4; ++r) {
            int row = m0 + w * 16 + fq * 4 + r;
            atomicAdd(&out[(size_t)row * NCLS + col], acc[nt][r]);
        }
    }
}

// ---------------- launch -----------------------------------------------------
extern "C" void kernel_launch(void* const* d_in, const int* in_sizes, int n_in,
                              void* d_out, int out_size, void* d_ws, size_t ws_size,
                              hipStream_t stream) {
    const float* inputs  = (const float*)d_in[0];
    const float* W_in    = (const float*)d_in[1];
    const float* conv_w  = (const float*)d_in[2];
    const float* conv_b  = (const float*)d_in[3];
    const float* dt_bias = (const float*)d_in[4];
    const float* A_log   = (const float*)d_in[5];
    const float* Dvec    = (const float*)d_in[6];
    const float* norm_w  = (const float*)d_in[7];
    // d_in[8] = W_out (unused by reference output)
    const float* W_cls   = (const float*)d_in[9];
    const float* b_cls   = (const float*)d_in[10];
    float* out = (float*)d_out;

    // workspace layout
    float* ws   = (float*)d_ws;
    unsigned short* zxb = (unsigned short*)ws;   // BL*4384 bf16
    float* xbc  = ws   + (size_t)BL * DINPROJ / 2 + 512;   // BL*2304 fp32
    float* dtb  = xbc  + (size_t)BL * CONVDIM;   // BL*32
    float* yb   = dtb  + (size_t)BL * NHEADS;    // BL*2048
    float* Sc_g = yb   + (size_t)BL * DINNER;    // 512*8192 (dead after k_chain; Gbf aliases it)
    float* lam_g= Sc_g + (size_t)BATCH * NHEADS * NCH * HEADDIM * DSTATE;  // 512
    float* esc_g= lam_g+ (size_t)BATCH * NHEADS * NCH;                     // 512*64
    unsigned short* Sin_bf = (unsigned short*)(esc_g + (size_t)BATCH * NHEADS * NCH * QC);
    unsigned short* abf    = Sin_bf + (size_t)BATCH * NHEADS * NCH * HEADDIM * DSTATE;
    unsigned short* wtbf   = abf + (size_t)BL * DMODEL;                    // 4480*1024 (padded)
    unsigned short* wclsbf = wtbf + (size_t)NPROJPAD * DMODEL;             // 48*2048
    unsigned short* Gbf    = (unsigned short*)Sc_g;  // alias: Sc_g is dead post-k_chain

    k_cvt_a<<<dim3(BL * DMODEL / (256 * 4)), dim3(256), 0, stream>>>(inputs, abf);
    k_transpose_w<<<dim3(DINPROJ / 32, DMODEL / 32), dim3(256), 0, stream>>>(W_in, wtbf);
    k_prep_cls<<<dim3(240), dim3(256), 0, stream>>>(W_cls, b_cls, wclsbf, out);
    k_gemm_in<<<dim3(NPROJPAD / 128, BL / 128), dim3(256), 0, stream>>>(abf, wtbf, zxb);
    k_conv_dt<<<dim3(10, BL), dim3(256), 0, stream>>>(zxb, conv_w, conv_b, dt_bias, xbc, dtb);
    k_chunk<<<dim3(BATCH * NHEADS * NCH), dim3(256), 0, stream>>>(xbc, dtb, A_log, Dvec,
                                                                  yb, Sc_g, lam_g, esc_g);
    k_chain<<<dim3(BATCH * NHEADS * 4), dim3(256), 0, stream>>>(Sc_g, lam_g, Sin_bf);
    k_cross<<<dim3(BATCH * NHEADS * NCH), dim3(256), 0, stream>>>(xbc, esc_g, Sin_bf, yb);
    k_gate_norm<<<dim3(BL), dim3(256), 0, stream>>>(zxb, norm_w, yb, Gbf);
    k_cls_mfma<<<dim3(BL / 64, 8), dim3(256), 0, stream>>>(Gbf, wclsbf, out);
}